// Round 6
// baseline (15624.069 us; speedup 1.0000x reference)
//
#include <hip/hip_runtime.h>
#include <hip/hip_bf16.h>

typedef __hip_bfloat16 bf16;
typedef short bf16x8 __attribute__((ext_vector_type(8)));   // 8 bf16 = 4 VGPRs
typedef float f32x4 __attribute__((ext_vector_type(4)));

// Problem constants
#define CB 2
#define CS 4096
#define CD 1024
#define CL 512
#define CST 64
#define CH 8
#define CT 640      // 2*ST + L
#define CDH 4096
#define NSEG 8
#define MCH 1024    // MLP M-chunk rows

__device__ __forceinline__ float tof(float x) { return x; }
__device__ __forceinline__ float tof(bf16 x) { return __bfloat162float(x); }
__device__ __forceinline__ void storev(float* p, float v) { *p = v; }
__device__ __forceinline__ void storev(bf16* p, float v) { *p = __float2bfloat16(v); }

// runtime-dtype input load: f32w!=0 -> buffer is float32, else bf16
__device__ __forceinline__ float ldin(const void* p, size_t i, int f32w) {
    if (f32w) return ((const float*)p)[i];
    return __bfloat162float(((const bf16*)p)[i]);
}

// ---------------------------------------------------------------------------
// Dtype sniffer (proven in round 2; resolves to flag=0 = bf16 on this bench).
// ---------------------------------------------------------------------------
__global__ void sniff_kernel(const void* x, int* flag) {
    if (threadIdx.x == 0 && blockIdx.x == 0) {
        const bf16* hb = (const bf16*)x;
        int plaus = 0;
        for (int i = 0; i < 256; ++i) {
            float v = __bfloat162float(hb[2 * i]);
            float a = fabsf(v);
            if (v == 0.f || (a > 1e-4f && a < 100.f)) ++plaus;
        }
        flag[0] = (plaus < 128) ? 1 : 0;
    }
}

// ---------------------------------------------------------------------------
// PROVEN (round 2) scalar tiled GEMM — kept for QKV and Wo projections.
// ---------------------------------------------------------------------------
template <typename TA, typename TC>
__global__ __launch_bounds__(256) void gemm_kernel(
    const TA* __restrict__ A,
    const void* __restrict__ B0, const void* __restrict__ B1, const void* __restrict__ B2,
    TC* __restrict__ C0, TC* __restrict__ C1, TC* __restrict__ C2,
    int M, int N, int K, const void* __restrict__ bias, int out_mode, int act,
    const int* __restrict__ flag)
{
    const int f32w = flag[0];
    const void* Bw = (blockIdx.z == 0) ? B0 : (blockIdx.z == 1 ? B1 : B2);
    TC* C = (blockIdx.z == 0) ? C0 : (blockIdx.z == 1 ? C1 : C2);

    __shared__ float As[16][65];
    __shared__ float Bs[16][65];

    int tid = threadIdx.x;
    int tx = tid & 15, ty = tid >> 4;
    int bm = blockIdx.x * 64, bn = blockIdx.y * 64;

    float acc[4][4] = {};

    for (int k0 = 0; k0 < K; k0 += 16) {
#pragma unroll
        for (int i = 0; i < 4; ++i) {
            int e = tid + i * 256;
            int r = e >> 4, c = e & 15;
            As[c][r] = tof(A[(size_t)(bm + r) * K + (k0 + c)]);
        }
#pragma unroll
        for (int i = 0; i < 4; ++i) {
            int e = tid + i * 256;
            int r = e >> 6, c = e & 63;
            Bs[r][c] = ldin(Bw, (size_t)(k0 + r) * N + (bn + c), f32w);
        }
        __syncthreads();
#pragma unroll
        for (int kk = 0; kk < 16; ++kk) {
            float av[4], bv[4];
#pragma unroll
            for (int i = 0; i < 4; ++i) av[i] = As[kk][ty * 4 + i];
#pragma unroll
            for (int j = 0; j < 4; ++j) bv[j] = Bs[kk][tx * 4 + j];
#pragma unroll
            for (int i = 0; i < 4; ++i)
#pragma unroll
                for (int j = 0; j < 4; ++j) acc[i][j] += av[i] * bv[j];
        }
        __syncthreads();
    }

#pragma unroll
    for (int i = 0; i < 4; ++i) {
        int r = bm + ty * 4 + i;
#pragma unroll
        for (int j = 0; j < 4; ++j) {
            int c = bn + tx * 4 + j;
            float v = acc[i][j];
            if (bias) v += ldin(bias, c, f32w);
            if (act == 1) v = 0.5f * v * (1.0f + erff(v * 0.70710678118654752f));
            size_t idx;
            if (out_mode == 0) {
                idx = (size_t)r * N + c;
            } else {
                int b = r / CT, t = r % CT, hh = c >> 6, k2 = c & 63;
                idx = ((size_t)(b * CH + hh) * CT + t) * 64 + k2;
            }
            storev(C + idx, v);
        }
    }
}

// ---------------------------------------------------------------------------
// DIAGNOSTIC MFMA GEMM for MLP only: C[M,N] = A[M,K](bf16) * B[K,N](flagged).
// No LDS, no pre-transpose, no aliasing. 4 waves (2x2), block tile 128x128,
// wave tile 64x64, 4x4 fragments of 16x16x32.
//   A frag: 16B vector load, row = bm+wm*64+mi*16+(lane&15), k = k0+(lane>>4)*8
//   B frag: 8 strided scalar loads from B[K][N]: col = bn+wn*64+nj*16+(lane&15)
// C/D layout: col=lane&15, row=(lane>>4)*4+reg  [m89]
// ---------------------------------------------------------------------------
template <typename TC, int ACT>
__global__ __launch_bounds__(256) void mfma_mlp(
    const bf16* __restrict__ A, const void* __restrict__ B, TC* __restrict__ C,
    const void* __restrict__ bias, int M, int N, int K, const int* __restrict__ flag)
{
    const int f32w = flag[0];
    const int tid = threadIdx.x;
    const int lane = tid & 63;
    const int w = tid >> 6;
    const int wm = w >> 1, wn = w & 1;
    const int bm = blockIdx.x * 128, bn = blockIdx.y * 128;
    const int rsub = lane & 15;
    const int ksub = (lane >> 4) * 8;

    const bf16* Abase = A + (size_t)(bm + wm * 64 + rsub) * K + ksub;
    const int ncol = bn + wn * 64 + rsub;

    f32x4 acc[4][4];
#pragma unroll
    for (int i = 0; i < 4; ++i)
#pragma unroll
        for (int j = 0; j < 4; ++j) acc[i][j] = (f32x4){0.f, 0.f, 0.f, 0.f};

    for (int k0 = 0; k0 < K; k0 += 32) {
        bf16x8 av[4], bv[4];
#pragma unroll
        for (int mi = 0; mi < 4; ++mi)
            av[mi] = *(const bf16x8*)(Abase + (size_t)mi * 16 * K + k0);
#pragma unroll
        for (int nj = 0; nj < 4; ++nj) {
            bf16x8 tmp;
#pragma unroll
            for (int j = 0; j < 8; ++j) {
                size_t idx = (size_t)(k0 + ksub + j) * N + ncol + nj * 16;
                short sv;
                if (f32w) {
                    bf16 t = __float2bfloat16(((const float*)B)[idx]);
                    sv = *(short*)&t;
                } else {
                    sv = ((const short*)B)[idx];
                }
                tmp[j] = sv;
            }
            bv[nj] = tmp;
        }
#pragma unroll
        for (int mi = 0; mi < 4; ++mi)
#pragma unroll
            for (int nj = 0; nj < 4; ++nj)
                acc[mi][nj] = __builtin_amdgcn_mfma_f32_16x16x32_bf16(
                    av[mi], bv[nj], acc[mi][nj], 0, 0, 0);
    }

#pragma unroll
    for (int mi = 0; mi < 4; ++mi) {
#pragma unroll
        for (int nj = 0; nj < 4; ++nj) {
            int c = bn + wn * 64 + nj * 16 + (lane & 15);
            float bia = bias ? ldin(bias, c, f32w) : 0.f;
#pragma unroll
            for (int r = 0; r < 4; ++r) {
                int row = bm + wm * 64 + mi * 16 + (lane >> 4) * 4 + r;
                float v = acc[mi][nj][r] + bia;
                if (ACT == 1) v = 0.5f * v * (1.0f + erff(v * 0.70710678118654752f));
                storev(C + (size_t)row * N + c, v);
            }
        }
    }
}

// ---------------------------------------------------------------------------
// Causal attention, one wave per (b, h, t) query row. lane = dim (64).
// ---------------------------------------------------------------------------
__global__ __launch_bounds__(64) void attn_kernel(
    const float* __restrict__ q, const float* __restrict__ k, const float* __restrict__ v,
    float* __restrict__ o, int ob, int oh, int ot)
{
    int t = blockIdx.x, hh = blockIdx.y, b = blockIdx.z;
    int lane = threadIdx.x;
    size_t base = (size_t)(b * CH + hh) * CT * 64;
    float qd = q[base + (size_t)t * 64 + lane];

    float m = -1e30f, l = 0.f, acc = 0.f;
    for (int j = 0; j <= t; ++j) {
        float prod = qd * k[base + (size_t)j * 64 + lane];
#pragma unroll
        for (int off = 32; off; off >>= 1) prod += __shfl_xor(prod, off);
        float s = prod * 0.125f;  // 1/sqrt(64)
        float mn = fmaxf(m, s);
        float corr = __expf(m - mn);
        float p = __expf(s - mn);
        l = l * corr + p;
        acc = acc * corr + p * v[base + (size_t)j * 64 + lane];
        m = mn;
    }
    o[(size_t)b * ob + (size_t)hh * oh + (size_t)t * ot + lane] = acc / l;
}

// ---------------------------------------------------------------------------
// Level-1 projections + RoPE. One wave per (b,h,t).
// ---------------------------------------------------------------------------
__global__ __launch_bounds__(64) void proj1_kernel(
    const float* __restrict__ o0,
    const void* __restrict__ Wq1, const void* __restrict__ Wk1, const void* __restrict__ Wv1,
    float* __restrict__ q1, float* __restrict__ k1, float* __restrict__ v1,
    const int* __restrict__ flag)
{
    const int f32w = flag[0];
    int t = blockIdx.x, hh = blockIdx.y, b = blockIdx.z;
    int lane = threadIdx.x;
    __shared__ float os[64];
    size_t rowoff = ((size_t)(b * CH + hh) * CT + t) * 64;
    os[lane] = o0[rowoff + lane];
    __syncthreads();

    size_t wbase = (size_t)hh * 64 * 64;
    float aq = 0.f, ak = 0.f, av = 0.f;
#pragma unroll 8
    for (int vv = 0; vv < 64; ++vv) {
        float ov = os[vv];
        aq += ov * ldin(Wq1, wbase + vv * 64 + lane, f32w);
        ak += ov * ldin(Wk1, wbase + vv * 64 + lane, f32w);
        av += ov * ldin(Wv1, wbase + vv * 64 + lane, f32w);
    }
    int i = lane >> 1;
    float inv = powf(10000.f, -(float)(2 * i) / 64.f);
    float ang = (float)t * inv;
    float sn, cs;
    sincosf(ang, &sn, &cs);
    float oq = __shfl_xor(aq, 1);
    float okk = __shfl_xor(ak, 1);
    float rq, rk;
    if (lane & 1) { rq = oq * sn + aq * cs; rk = okk * sn + ak * cs; }
    else          { rq = aq * cs - oq * sn; rk = ak * cs - okk * sn; }
    q1[rowoff + lane] = rq;
    k1[rowoff + lane] = rk;
    v1[rowoff + lane] = av;
}

// RoPE over q0 and k0: [B][H][T][64], thread per (bh,t,pair)
__global__ __launch_bounds__(256) void rope_qk_kernel(float* __restrict__ q, float* __restrict__ k)
{
    int idx = blockIdx.x * 256 + threadIdx.x;  // B*H*T*32
    int i = idx & 31;
    int t = (idx >> 5) % CT;
    int bh = idx / (32 * CT);
    float inv = powf(10000.f, -(float)(2 * i) / 64.f);
    float ang = (float)t * inv;
    float sn, cs;
    sincosf(ang, &sn, &cs);
    size_t p = ((size_t)bh * CT + t) * 64 + 2 * i;
    float x1 = q[p], x2 = q[p + 1];
    q[p] = x1 * cs - x2 * sn;
    q[p + 1] = x1 * sn + x2 * cs;
    x1 = k[p]; x2 = k[p + 1];
    k[p] = x1 * cs - x2 * sn;
    k[p + 1] = x1 * sn + x2 * cs;
}

// toks = concat([state, x_seg, state]) along t (fp32, as in round 2)
__global__ __launch_bounds__(256) void build_toks_kernel(
    const void* __restrict__ x, const float* __restrict__ state, float* __restrict__ toks,
    int seg, const int* __restrict__ flag)
{
    const int f32w = flag[0];
    int idx = blockIdx.x * 256 + threadIdx.x;  // B*T*D
    int d = idx & (CD - 1);
    int t = (idx >> 10) % CT;
    int b = idx / (CT * CD);
    float v;
    if (t < CST) v = state[(b * CST + t) * CD + d];
    else if (t < CST + CL) v = ldin(x, ((size_t)b * CS + seg * CL + (t - CST)) * CD + d, f32w);
    else v = state[(b * CST + (t - CST - CL)) * CD + d];
    toks[idx] = v;
}

// split seg_out: middle L tokens -> a, last ST tokens -> state
__global__ __launch_bounds__(256) void seg_epi_kernel(
    const float* __restrict__ seg_out, float* __restrict__ a, float* __restrict__ state, int seg)
{
    int idx = blockIdx.x * 256 + threadIdx.x;  // B*(T-ST)*D
    int d = idx & (CD - 1);
    int tt = (idx >> 10) % (CT - CST);
    int b = idx / ((CT - CST) * CD);
    float v = seg_out[((size_t)b * CT + (tt + CST)) * CD + d];
    if (tt < CL) a[((size_t)b * CS + seg * CL + tt) * CD + d] = v;
    else state[(b * CST + (tt - CL)) * CD + d] = v;
}

__global__ __launch_bounds__(256) void init_state_kernel(
    const void* __restrict__ s0, float* __restrict__ state, const int* __restrict__ flag)
{
    const int f32w = flag[0];
    int idx = blockIdx.x * 256 + threadIdx.x;  // B*ST*D
    state[idx] = ldin(s0, idx % (CST * CD), f32w);
}

// LayerNorm(ra + x) * g + b.
__global__ __launch_bounds__(256) void ln_kernel(
    const float* __restrict__ ra, const void* __restrict__ x,
    const void* __restrict__ g, const void* __restrict__ bb,
    void* __restrict__ outp, int out_ext, const int* __restrict__ flag)
{
    const int f32w = flag[0];
    int row = blockIdx.x;
    int tid = threadIdx.x;
    __shared__ float buf[CD];
    __shared__ float red[4];

    float s = 0.f;
    for (int c = tid; c < CD; c += 256) {
        float v = ra[(size_t)row * CD + c] + ldin(x, (size_t)row * CD + c, f32w);
        buf[c] = v;
        s += v;
    }
#pragma unroll
    for (int off = 32; off; off >>= 1) s += __shfl_xor(s, off);
    if ((tid & 63) == 0) red[tid >> 6] = s;
    __syncthreads();
    float mu = (red[0] + red[1] + red[2] + red[3]) * (1.f / CD);
    __syncthreads();

    float vs = 0.f;
    for (int c = tid; c < CD; c += 256) {
        float d0 = buf[c] - mu;
        vs += d0 * d0;
    }
#pragma unroll
    for (int off = 32; off; off >>= 1) vs += __shfl_xor(vs, off);
    if ((tid & 63) == 0) red[tid >> 6] = vs;
    __syncthreads();
    float var = (red[0] + red[1] + red[2] + red[3]) * (1.f / CD);
    float rs = rsqrtf(var + 1e-5f);

    for (int c = tid; c < CD; c += 256) {
        float y = (buf[c] - mu) * rs * ldin(g, c, f32w) + ldin(bb, c, f32w);
        size_t idx = (size_t)row * CD + c;
        if (!out_ext) {
            ((bf16*)outp)[idx] = __float2bfloat16(y);
        } else if (f32w) {
            ((float*)outp)[idx] = y;
        } else {
            ((bf16*)outp)[idx] = __float2bfloat16(y);
        }
    }
}

extern "C" void kernel_launch(void* const* d_in, const int* in_sizes, int n_in,
                              void* d_out, int out_size, void* d_ws, size_t ws_size,
                              hipStream_t stream)
{
    const void* x      = d_in[0];
    const void* s0     = d_in[1];
    const void* Wq0    = d_in[2];
    const void* Wk0    = d_in[3];
    const void* Wv0    = d_in[4];
    const void* Wq1    = d_in[5];
    const void* Wk1    = d_in[6];
    const void* Wv1    = d_in[7];
    const void* Wo     = d_in[8];
    const void* bo     = d_in[9];
    const void* g_attn = d_in[10];
    const void* b_attn = d_in[11];
    const void* W1     = d_in[12];
    const void* b1     = d_in[13];
    const void* W2     = d_in[14];
    const void* b2     = d_in[15];
    const void* g_mlp  = d_in[16];
    const void* b_mlp  = d_in[17];

    // workspace carve-up (byte-identical to passing round 2): ~91 MB
    int* flag = (int*)d_ws;
    float* f = (float*)((char*)d_ws + 16);
    float* toks = f;    f += (size_t)CB * CT * CD;
    float* q0 = f;      f += (size_t)CB * CH * CT * 64;
    float* k0 = f;      f += (size_t)CB * CH * CT * 64;
    float* v0 = f;      f += (size_t)CB * CH * CT * 64;
    float* o0 = f;      f += (size_t)CB * CH * CT * 64;
    float* q1 = f;      f += (size_t)CB * CH * CT * 64;
    float* k1 = f;      f += (size_t)CB * CH * CT * 64;
    float* v1 = f;      f += (size_t)CB * CH * CT * 64;
    float* o1t = f;     f += (size_t)CB * CT * (CH * 64); // [b][t][h*64+v]
    float* seg_out = f; f += (size_t)CB * CT * CD;
    float* state = f;   f += (size_t)CB * CST * CD;
    float* a = f;       f += (size_t)CB * CS * CD;
    bf16* h = (bf16*)f;                                   // LN1 out [B*S, D] bf16
    bf16* g1 = h + (size_t)CB * CS * CD;                  // MLP mid chunk [MCH, DH] bf16

    sniff_kernel<<<1, 64, 0, stream>>>(x, flag);
    init_state_kernel<<<(CB * CST * CD) / 256, 256, 0, stream>>>(s0, state, flag);

    for (int seg = 0; seg < NSEG; ++seg) {
        build_toks_kernel<<<(CB * CT * CD) / 256, 256, 0, stream>>>(x, state, toks, seg, flag);
        gemm_kernel<float, float><<<dim3(20, 8, 3), 256, 0, stream>>>(
            toks, Wq0, Wk0, Wv0, q0, k0, v0, CB * CT, CH * 64, CD, nullptr, 1, 0, flag);
        rope_qk_kernel<<<(CB * CH * CT * 32) / 256, 256, 0, stream>>>(q0, k0);
        attn_kernel<<<dim3(CT, CH, CB), 64, 0, stream>>>(
            q0, k0, v0, o0, CH * CT * 64, CT * 64, 64);
        proj1_kernel<<<dim3(CT, CH, CB), 64, 0, stream>>>(o0, Wq1, Wk1, Wv1, q1, k1, v1, flag);
        attn_kernel<<<dim3(CT, CH, CB), 64, 0, stream>>>(
            q1, k1, v1, o1t, CT * (CH * 64), 64, CH * 64);
        gemm_kernel<float, float><<<dim3(20, 16, 1), 256, 0, stream>>>(
            o1t, Wo, Wo, Wo, seg_out, seg_out, seg_out, CB * CT, CD, CH * 64, bo, 0, 0, flag);
        seg_epi_kernel<<<(CB * (CT - CST) * CD) / 256, 256, 0, stream>>>(seg_out, a, state, seg);
    }

    // h = LN(a + x) -> bf16 internal
    ln_kernel<<<CB * CS, 256, 0, stream>>>(a, x, g_attn, b_attn, h, 0, flag);
    // MLP in M-chunks of 1024 rows — THE ONLY CHANGE vs round 2: MFMA kernels
    for (int c = 0; c < (CB * CS) / MCH; ++c) {
        mfma_mlp<bf16, 1><<<dim3(MCH / 128, CDH / 128), 256, 0, stream>>>(
            h + (size_t)c * MCH * CD, W1, g1, b1, MCH, CDH, CD, flag);
        mfma_mlp<float, 0><<<dim3(MCH / 128, CD / 128), 256, 0, stream>>>(
            g1, W2, a + (size_t)c * MCH * CD, b2, MCH, CD, CDH, flag);
    }
    // out = LN(m + x) -> flagged external dtype
    ln_kernel<<<CB * CS, 256, 0, stream>>>(a, x, g_mlp, b_mlp, d_out, 1, flag);
}

// Round 7
// 9234.887 us; speedup vs baseline: 1.6919x; 1.6919x over previous
//
#include <hip/hip_runtime.h>
#include <hip/hip_bf16.h>

typedef __hip_bfloat16 bf16;
typedef short bf16x8 __attribute__((ext_vector_type(8)));   // 8 bf16 = 4 VGPRs
typedef float f32x4 __attribute__((ext_vector_type(4)));

// Problem constants
#define CB 2
#define CS 4096
#define CD 1024
#define CL 512
#define CST 64
#define CH 8
#define CT 640      // 2*ST + L
#define CDH 4096
#define NSEG 8
#define MCH 1024    // MLP M-chunk rows

__device__ __forceinline__ float tof(float x) { return x; }
__device__ __forceinline__ float tof(bf16 x) { return __bfloat162float(x); }
__device__ __forceinline__ void storev(float* p, float v) { *p = v; }
__device__ __forceinline__ void storev(bf16* p, float v) { *p = __float2bfloat16(v); }

// runtime-dtype input load: f32w!=0 -> buffer is float32, else bf16
__device__ __forceinline__ float ldin(const void* p, size_t i, int f32w) {
    if (f32w) return ((const float*)p)[i];
    return __bfloat162float(((const bf16*)p)[i]);
}

// ---------------------------------------------------------------------------
// Dtype sniffer (proven round 2/6; resolves flag=0 = bf16 on this bench).
// ---------------------------------------------------------------------------
__global__ void sniff_kernel(const void* x, int* flag) {
    if (threadIdx.x == 0 && blockIdx.x == 0) {
        const bf16* hb = (const bf16*)x;
        int plaus = 0;
        for (int i = 0; i < 256; ++i) {
            float v = __bfloat162float(hb[2 * i]);
            float a = fabsf(v);
            if (v == 0.f || (a > 1e-4f && a < 100.f)) ++plaus;
        }
        flag[0] = (plaus < 128) ? 1 : 0;
    }
}

// ---------------------------------------------------------------------------
// PROVEN (round 2) scalar tiled GEMM — kept for QKV and Wo projections.
// ---------------------------------------------------------------------------
template <typename TA, typename TC>
__global__ __launch_bounds__(256) void gemm_kernel(
    const TA* __restrict__ A,
    const void* __restrict__ B0, const void* __restrict__ B1, const void* __restrict__ B2,
    TC* __restrict__ C0, TC* __restrict__ C1, TC* __restrict__ C2,
    int M, int N, int K, const void* __restrict__ bias, int out_mode, int act,
    const int* __restrict__ flag)
{
    const int f32w = flag[0];
    const void* Bw = (blockIdx.z == 0) ? B0 : (blockIdx.z == 1 ? B1 : B2);
    TC* C = (blockIdx.z == 0) ? C0 : (blockIdx.z == 1 ? C1 : C2);

    __shared__ float As[16][65];
    __shared__ float Bs[16][65];

    int tid = threadIdx.x;
    int tx = tid & 15, ty = tid >> 4;
    int bm = blockIdx.x * 64, bn = blockIdx.y * 64;

    float acc[4][4] = {};

    for (int k0 = 0; k0 < K; k0 += 16) {
#pragma unroll
        for (int i = 0; i < 4; ++i) {
            int e = tid + i * 256;
            int r = e >> 4, c = e & 15;
            As[c][r] = tof(A[(size_t)(bm + r) * K + (k0 + c)]);
        }
#pragma unroll
        for (int i = 0; i < 4; ++i) {
            int e = tid + i * 256;
            int r = e >> 6, c = e & 63;
            Bs[r][c] = ldin(Bw, (size_t)(k0 + r) * N + (bn + c), f32w);
        }
        __syncthreads();
#pragma unroll
        for (int kk = 0; kk < 16; ++kk) {
            float av[4], bv[4];
#pragma unroll
            for (int i = 0; i < 4; ++i) av[i] = As[kk][ty * 4 + i];
#pragma unroll
            for (int j = 0; j < 4; ++j) bv[j] = Bs[kk][tx * 4 + j];
#pragma unroll
            for (int i = 0; i < 4; ++i)
#pragma unroll
                for (int j = 0; j < 4; ++j) acc[i][j] += av[i] * bv[j];
        }
        __syncthreads();
    }

#pragma unroll
    for (int i = 0; i < 4; ++i) {
        int r = bm + ty * 4 + i;
#pragma unroll
        for (int j = 0; j < 4; ++j) {
            int c = bn + tx * 4 + j;
            float v = acc[i][j];
            if (bias) v += ldin(bias, c, f32w);
            if (act == 1) v = 0.5f * v * (1.0f + erff(v * 0.70710678118654752f));
            size_t idx;
            if (out_mode == 0) {
                idx = (size_t)r * N + c;
            } else {
                int b = r / CT, t = r % CT, hh = c >> 6, k2 = c & 63;
                idx = ((size_t)(b * CH + hh) * CT + t) * 64 + k2;
            }
            storev(C + idx, v);
        }
    }
}

// ---------------------------------------------------------------------------
// bf16 transpose: out[C][R] = in[R][C], 64x64 tiles. Honors dtype flag on in.
// ---------------------------------------------------------------------------
__global__ __launch_bounds__(256) void transpose_kernel(
    const void* __restrict__ in, bf16* __restrict__ out, int R, int C,
    const int* __restrict__ flag)
{
    const int f32w = flag[0];
    __shared__ short t[64][72];
    int tid = threadIdx.x;
    int c0 = blockIdx.x * 64, r0 = blockIdx.y * 64;
    int cc = tid & 63, rr = tid >> 6;
#pragma unroll
    for (int i = 0; i < 16; ++i) {
        bf16 v = __float2bfloat16(ldin(in, (size_t)(r0 + rr + i * 4) * C + c0 + cc, f32w));
        t[rr + i * 4][cc] = *(short*)&v;
    }
    __syncthreads();
#pragma unroll
    for (int i = 0; i < 16; ++i)
        ((short*)out)[(size_t)(c0 + rr + i * 4) * R + r0 + cc] = t[cc][rr + i * 4];
}

// ---------------------------------------------------------------------------
// MFMA GEMM, vector loads both operands: C[M,N] = A[M,K](bf16) * Bt[N,K]^T.
// A-fragment mechanics PROVEN in round 6; B is now symmetric to A.
// 4 waves (2x2), block tile 128x128, wave tile 64x64, no LDS.
// C/D layout: col=lane&15, row=(lane>>4)*4+reg  [round-6 proven]
// ---------------------------------------------------------------------------
template <typename TC, int ACT>
__global__ __launch_bounds__(256) void mfma_mlp2(
    const bf16* __restrict__ A, const bf16* __restrict__ Bt, TC* __restrict__ C,
    const void* __restrict__ bias, int M, int N, int K, const int* __restrict__ flag)
{
    const int f32w = flag[0];
    const int tid = threadIdx.x;
    const int lane = tid & 63;
    const int w = tid >> 6;
    const int wm = w >> 1, wn = w & 1;
    const int bm = blockIdx.x * 128, bn = blockIdx.y * 128;
    const int rsub = lane & 15;
    const int ksub = (lane >> 4) * 8;

    const bf16* Abase = A + (size_t)(bm + wm * 64 + rsub) * K + ksub;
    const bf16* Bbase = Bt + (size_t)(bn + wn * 64 + rsub) * K + ksub;

    f32x4 acc[4][4];
#pragma unroll
    for (int i = 0; i < 4; ++i)
#pragma unroll
        for (int j = 0; j < 4; ++j) acc[i][j] = (f32x4){0.f, 0.f, 0.f, 0.f};

    for (int k0 = 0; k0 < K; k0 += 64) {
        bf16x8 av[2][4], bv[2][4];
#pragma unroll
        for (int kh = 0; kh < 2; ++kh) {
#pragma unroll
            for (int mi = 0; mi < 4; ++mi)
                av[kh][mi] = *(const bf16x8*)(Abase + (size_t)mi * 16 * K + k0 + kh * 32);
#pragma unroll
            for (int nj = 0; nj < 4; ++nj)
                bv[kh][nj] = *(const bf16x8*)(Bbase + (size_t)nj * 16 * K + k0 + kh * 32);
        }
#pragma unroll
        for (int kh = 0; kh < 2; ++kh)
#pragma unroll
            for (int mi = 0; mi < 4; ++mi)
#pragma unroll
                for (int nj = 0; nj < 4; ++nj)
                    acc[mi][nj] = __builtin_amdgcn_mfma_f32_16x16x32_bf16(
                        av[kh][mi], bv[kh][nj], acc[mi][nj], 0, 0, 0);
    }

#pragma unroll
    for (int mi = 0; mi < 4; ++mi) {
#pragma unroll
        for (int nj = 0; nj < 4; ++nj) {
            int c = bn + wn * 64 + nj * 16 + (lane & 15);
            float bia = bias ? ldin(bias, c, f32w) : 0.f;
#pragma unroll
            for (int r = 0; r < 4; ++r) {
                int row = bm + wm * 64 + mi * 16 + (lane >> 4) * 4 + r;
                float v = acc[mi][nj][r] + bia;
                if (ACT == 1) v = 0.5f * v * (1.0f + erff(v * 0.70710678118654752f));
                storev(C + (size_t)row * N + c, v);
            }
        }
    }
}

// ---------------------------------------------------------------------------
// Causal attention, one wave per (b, h, t) query row. lane = dim (64).
// ---------------------------------------------------------------------------
__global__ __launch_bounds__(64) void attn_kernel(
    const float* __restrict__ q, const float* __restrict__ k, const float* __restrict__ v,
    float* __restrict__ o, int ob, int oh, int ot)
{
    int t = blockIdx.x, hh = blockIdx.y, b = blockIdx.z;
    int lane = threadIdx.x;
    size_t base = (size_t)(b * CH + hh) * CT * 64;
    float qd = q[base + (size_t)t * 64 + lane];

    float m = -1e30f, l = 0.f, acc = 0.f;
    for (int j = 0; j <= t; ++j) {
        float prod = qd * k[base + (size_t)j * 64 + lane];
#pragma unroll
        for (int off = 32; off; off >>= 1) prod += __shfl_xor(prod, off);
        float s = prod * 0.125f;  // 1/sqrt(64)
        float mn = fmaxf(m, s);
        float corr = __expf(m - mn);
        float p = __expf(s - mn);
        l = l * corr + p;
        acc = acc * corr + p * v[base + (size_t)j * 64 + lane];
        m = mn;
    }
    o[(size_t)b * ob + (size_t)hh * oh + (size_t)t * ot + lane] = acc / l;
}

// ---------------------------------------------------------------------------
// Level-1 projections + RoPE. One wave per (b,h,t).
// ---------------------------------------------------------------------------
__global__ __launch_bounds__(64) void proj1_kernel(
    const float* __restrict__ o0,
    const void* __restrict__ Wq1, const void* __restrict__ Wk1, const void* __restrict__ Wv1,
    float* __restrict__ q1, float* __restrict__ k1, float* __restrict__ v1,
    const int* __restrict__ flag)
{
    const int f32w = flag[0];
    int t = blockIdx.x, hh = blockIdx.y, b = blockIdx.z;
    int lane = threadIdx.x;
    __shared__ float os[64];
    size_t rowoff = ((size_t)(b * CH + hh) * CT + t) * 64;
    os[lane] = o0[rowoff + lane];
    __syncthreads();

    size_t wbase = (size_t)hh * 64 * 64;
    float aq = 0.f, ak = 0.f, av = 0.f;
#pragma unroll 8
    for (int vv = 0; vv < 64; ++vv) {
        float ov = os[vv];
        aq += ov * ldin(Wq1, wbase + vv * 64 + lane, f32w);
        ak += ov * ldin(Wk1, wbase + vv * 64 + lane, f32w);
        av += ov * ldin(Wv1, wbase + vv * 64 + lane, f32w);
    }
    int i = lane >> 1;
    float inv = powf(10000.f, -(float)(2 * i) / 64.f);
    float ang = (float)t * inv;
    float sn, cs;
    sincosf(ang, &sn, &cs);
    float oq = __shfl_xor(aq, 1);
    float okk = __shfl_xor(ak, 1);
    float rq, rk;
    if (lane & 1) { rq = oq * sn + aq * cs; rk = okk * sn + ak * cs; }
    else          { rq = aq * cs - oq * sn; rk = ak * cs - okk * sn; }
    q1[rowoff + lane] = rq;
    k1[rowoff + lane] = rk;
    v1[rowoff + lane] = av;
}

// RoPE over q0 and k0: [B][H][T][64], thread per (bh,t,pair)
__global__ __launch_bounds__(256) void rope_qk_kernel(float* __restrict__ q, float* __restrict__ k)
{
    int idx = blockIdx.x * 256 + threadIdx.x;  // B*H*T*32
    int i = idx & 31;
    int t = (idx >> 5) % CT;
    int bh = idx / (32 * CT);
    float inv = powf(10000.f, -(float)(2 * i) / 64.f);
    float ang = (float)t * inv;
    float sn, cs;
    sincosf(ang, &sn, &cs);
    size_t p = ((size_t)bh * CT + t) * 64 + 2 * i;
    float x1 = q[p], x2 = q[p + 1];
    q[p] = x1 * cs - x2 * sn;
    q[p + 1] = x1 * sn + x2 * cs;
    x1 = k[p]; x2 = k[p + 1];
    k[p] = x1 * cs - x2 * sn;
    k[p + 1] = x1 * sn + x2 * cs;
}

// toks = concat([state, x_seg, state]) along t (fp32)
__global__ __launch_bounds__(256) void build_toks_kernel(
    const void* __restrict__ x, const float* __restrict__ state, float* __restrict__ toks,
    int seg, const int* __restrict__ flag)
{
    const int f32w = flag[0];
    int idx = blockIdx.x * 256 + threadIdx.x;  // B*T*D
    int d = idx & (CD - 1);
    int t = (idx >> 10) % CT;
    int b = idx / (CT * CD);
    float v;
    if (t < CST) v = state[(b * CST + t) * CD + d];
    else if (t < CST + CL) v = ldin(x, ((size_t)b * CS + seg * CL + (t - CST)) * CD + d, f32w);
    else v = state[(b * CST + (t - CST - CL)) * CD + d];
    toks[idx] = v;
}

// split seg_out: middle L tokens -> a, last ST tokens -> state
__global__ __launch_bounds__(256) void seg_epi_kernel(
    const float* __restrict__ seg_out, float* __restrict__ a, float* __restrict__ state, int seg)
{
    int idx = blockIdx.x * 256 + threadIdx.x;  // B*(T-ST)*D
    int d = idx & (CD - 1);
    int tt = (idx >> 10) % (CT - CST);
    int b = idx / ((CT - CST) * CD);
    float v = seg_out[((size_t)b * CT + (tt + CST)) * CD + d];
    if (tt < CL) a[((size_t)b * CS + seg * CL + tt) * CD + d] = v;
    else state[(b * CST + (tt - CL)) * CD + d] = v;
}

__global__ __launch_bounds__(256) void init_state_kernel(
    const void* __restrict__ s0, float* __restrict__ state, const int* __restrict__ flag)
{
    const int f32w = flag[0];
    int idx = blockIdx.x * 256 + threadIdx.x;  // B*ST*D
    state[idx] = ldin(s0, idx % (CST * CD), f32w);
}

// LayerNorm(ra + x) * g + b.
__global__ __launch_bounds__(256) void ln_kernel(
    const float* __restrict__ ra, const void* __restrict__ x,
    const void* __restrict__ g, const void* __restrict__ bb,
    void* __restrict__ outp, int out_ext, const int* __restrict__ flag)
{
    const int f32w = flag[0];
    int row = blockIdx.x;
    int tid = threadIdx.x;
    __shared__ float buf[CD];
    __shared__ float red[4];

    float s = 0.f;
    for (int c = tid; c < CD; c += 256) {
        float v = ra[(size_t)row * CD + c] + ldin(x, (size_t)row * CD + c, f32w);
        buf[c] = v;
        s += v;
    }
#pragma unroll
    for (int off = 32; off; off >>= 1) s += __shfl_xor(s, off);
    if ((tid & 63) == 0) red[tid >> 6] = s;
    __syncthreads();
    float mu = (red[0] + red[1] + red[2] + red[3]) * (1.f / CD);
    __syncthreads();

    float vs = 0.f;
    for (int c = tid; c < CD; c += 256) {
        float d0 = buf[c] - mu;
        vs += d0 * d0;
    }
#pragma unroll
    for (int off = 32; off; off >>= 1) vs += __shfl_xor(vs, off);
    if ((tid & 63) == 0) red[tid >> 6] = vs;
    __syncthreads();
    float var = (red[0] + red[1] + red[2] + red[3]) * (1.f / CD);
    float rs = rsqrtf(var + 1e-5f);

    for (int c = tid; c < CD; c += 256) {
        float y = (buf[c] - mu) * rs * ldin(g, c, f32w) + ldin(bb, c, f32w);
        size_t idx = (size_t)row * CD + c;
        if (!out_ext) {
            ((bf16*)outp)[idx] = __float2bfloat16(y);
        } else if (f32w) {
            ((float*)outp)[idx] = y;
        } else {
            ((bf16*)outp)[idx] = __float2bfloat16(y);
        }
    }
}

extern "C" void kernel_launch(void* const* d_in, const int* in_sizes, int n_in,
                              void* d_out, int out_size, void* d_ws, size_t ws_size,
                              hipStream_t stream)
{
    const void* x      = d_in[0];
    const void* s0     = d_in[1];
    const void* Wq0    = d_in[2];
    const void* Wk0    = d_in[3];
    const void* Wv0    = d_in[4];
    const void* Wq1    = d_in[5];
    const void* Wk1    = d_in[6];
    const void* Wv1    = d_in[7];
    const void* Wo     = d_in[8];
    const void* bo     = d_in[9];
    const void* g_attn = d_in[10];
    const void* b_attn = d_in[11];
    const void* W1     = d_in[12];
    const void* b1     = d_in[13];
    const void* W2     = d_in[14];
    const void* b2     = d_in[15];
    const void* g_mlp  = d_in[16];
    const void* b_mlp  = d_in[17];

    // workspace carve-up (byte-identical to passing rounds 2/6): ~90.7 MB
    int* flag = (int*)d_ws;
    float* f = (float*)((char*)d_ws + 16);
    float* toks = f;    f += (size_t)CB * CT * CD;
    float* q0 = f;      f += (size_t)CB * CH * CT * 64;
    float* k0 = f;      f += (size_t)CB * CH * CT * 64;
    float* v0 = f;      f += (size_t)CB * CH * CT * 64;
    float* o0 = f;      f += (size_t)CB * CH * CT * 64;
    float* q1 = f;      f += (size_t)CB * CH * CT * 64;
    float* k1 = f;      f += (size_t)CB * CH * CT * 64;
    float* v1 = f;      f += (size_t)CB * CH * CT * 64;
    float* o1t = f;     f += (size_t)CB * CT * (CH * 64); // [b][t][h*64+v]
    float* seg_out = f; f += (size_t)CB * CT * CD;
    float* state = f;   f += (size_t)CB * CST * CD;
    float* a = f;       f += (size_t)CB * CS * CD;
    bf16* h = (bf16*)f;                                   // LN1 out [B*S, D] bf16
    bf16* g1 = h + (size_t)CB * CS * CD;                  // MLP mid chunk [MCH, DH] bf16
    // transposed MLP weights live in the SEGMENT-DEAD region (toks..state,
    // 32.0 MB dead during the MLP phase); written after the segment loop.
    bf16* Wt1 = (bf16*)toks;                              // [CDH][CD]  8.39 MB
    bf16* Wt2 = Wt1 + (size_t)CDH * CD;                   // [CD][CDH]  8.39 MB (ends 16.8 MB < 32 MB)

    sniff_kernel<<<1, 64, 0, stream>>>(x, flag);
    init_state_kernel<<<(CB * CST * CD) / 256, 256, 0, stream>>>(s0, state, flag);

    for (int seg = 0; seg < NSEG; ++seg) {
        build_toks_kernel<<<(CB * CT * CD) / 256, 256, 0, stream>>>(x, state, toks, seg, flag);
        gemm_kernel<float, float><<<dim3(20, 8, 3), 256, 0, stream>>>(
            toks, Wq0, Wk0, Wv0, q0, k0, v0, CB * CT, CH * 64, CD, nullptr, 1, 0, flag);
        rope_qk_kernel<<<(CB * CH * CT * 32) / 256, 256, 0, stream>>>(q0, k0);
        attn_kernel<<<dim3(CT, CH, CB), 64, 0, stream>>>(
            q0, k0, v0, o0, CH * CT * 64, CT * 64, 64);
        proj1_kernel<<<dim3(CT, CH, CB), 64, 0, stream>>>(o0, Wq1, Wk1, Wv1, q1, k1, v1, flag);
        attn_kernel<<<dim3(CT, CH, CB), 64, 0, stream>>>(
            q1, k1, v1, o1t, CT * (CH * 64), 64, CH * 64);
        gemm_kernel<float, float><<<dim3(20, 16, 1), 256, 0, stream>>>(
            o1t, Wo, Wo, Wo, seg_out, seg_out, seg_out, CB * CT, CD, CH * 64, bo, 0, 0, flag);
        seg_epi_kernel<<<(CB * (CT - CST) * CD) / 256, 256, 0, stream>>>(seg_out, a, state, seg);
    }

    // h = LN(a + x) -> bf16 internal
    ln_kernel<<<CB * CS, 256, 0, stream>>>(a, x, g_attn, b_attn, h, 0, flag);

    // transpose MLP weights into the now-dead segment region
    transpose_kernel<<<dim3(CDH / 64, CD / 64), 256, 0, stream>>>(W1, Wt1, CD, CDH, flag);
    transpose_kernel<<<dim3(CD / 64, CDH / 64), 256, 0, stream>>>(W2, Wt2, CDH, CD, flag);

    // MLP in M-chunks of 1024 rows, MFMA with vector-loaded Bt fragments
    for (int c = 0; c < (CB * CS) / MCH; ++c) {
        mfma_mlp2<bf16, 1><<<dim3(MCH / 128, CDH / 128), 256, 0, stream>>>(
            h + (size_t)c * MCH * CD, Wt1, g1, b1, MCH, CDH, CD, flag);
        mfma_mlp2<float, 0><<<dim3(MCH / 128, CD / 128), 256, 0, stream>>>(
            g1, Wt2, a + (size_t)c * MCH * CD, b2, MCH, CD, CDH, flag);
    }
    // out = LN(m + x) -> flagged external dtype
    ln_kernel<<<CB * CS, 256, 0, stream>>>(a, x, g_mlp, b_mlp, d_out, 1, flag);
}

// Round 8
// 4406.650 us; speedup vs baseline: 3.5456x; 2.0957x over previous
//
#include <hip/hip_runtime.h>
#include <hip/hip_bf16.h>

typedef __hip_bfloat16 bf16;
typedef short bf16x8 __attribute__((ext_vector_type(8)));   // 8 bf16 = 4 VGPRs
typedef float f32x4 __attribute__((ext_vector_type(4)));

// Problem constants
#define CB 2
#define CS 4096
#define CD 1024
#define CL 512
#define CST 64
#define CH 8
#define CT 640      // 2*ST + L
#define CDH 4096
#define NSEG 8
#define MCH 1024    // MLP M-chunk rows

__device__ __forceinline__ float tof(float x) { return x; }
__device__ __forceinline__ float tof(bf16 x) { return __bfloat162float(x); }
__device__ __forceinline__ void storev(float* p, float v) { *p = v; }
__device__ __forceinline__ void storev(bf16* p, float v) { *p = __float2bfloat16(v); }

// runtime-dtype input load: f32w!=0 -> buffer is float32, else bf16
__device__ __forceinline__ float ldin(const void* p, size_t i, int f32w) {
    if (f32w) return ((const float*)p)[i];
    return __bfloat162float(((const bf16*)p)[i]);
}

// ---------------------------------------------------------------------------
// Dtype sniffer (proven rounds 2/6/7; resolves flag=0 = bf16 on this bench).
// ---------------------------------------------------------------------------
__global__ void sniff_kernel(const void* x, int* flag) {
    if (threadIdx.x == 0 && blockIdx.x == 0) {
        const bf16* hb = (const bf16*)x;
        int plaus = 0;
        for (int i = 0; i < 256; ++i) {
            float v = __bfloat162float(hb[2 * i]);
            float a = fabsf(v);
            if (v == 0.f || (a > 1e-4f && a < 100.f)) ++plaus;
        }
        flag[0] = (plaus < 128) ? 1 : 0;
    }
}

// ---------------------------------------------------------------------------
// bf16 transpose: out[C][R] = in[R][C], 64x64 tiles. Honors dtype flag on in.
// PROVEN round 7.
// ---------------------------------------------------------------------------
__global__ __launch_bounds__(256) void transpose_kernel(
    const void* __restrict__ in, bf16* __restrict__ out, int R, int C,
    const int* __restrict__ flag)
{
    const int f32w = flag[0];
    __shared__ short t[64][72];
    int tid = threadIdx.x;
    int c0 = blockIdx.x * 64, r0 = blockIdx.y * 64;
    int cc = tid & 63, rr = tid >> 6;
#pragma unroll
    for (int i = 0; i < 16; ++i) {
        bf16 v = __float2bfloat16(ldin(in, (size_t)(r0 + rr + i * 4) * C + c0 + cc, f32w));
        t[rr + i * 4][cc] = *(short*)&v;
    }
    __syncthreads();
#pragma unroll
    for (int i = 0; i < 16; ++i)
        ((short*)out)[(size_t)(c0 + rr + i * 4) * R + r0 + cc] = t[cc][rr + i * 4];
}

// ---------------------------------------------------------------------------
// MFMA GEMM, vector loads both operands (PROVEN round 7 as mfma_mlp2), plus
// the round-2-proven triple-(Bt,C) blockIdx.z select for fused QKV.
// C[M,N] = A[M,K](bf16) * Bt[N,K]^T(bf16), row-major C, optional bias+GELU.
// 4 waves (2x2), block tile 128x128, wave tile 64x64, no LDS.
// ---------------------------------------------------------------------------
template <typename TC, int ACT>
__global__ __launch_bounds__(256) void mfma_nt(
    const bf16* __restrict__ A,
    const bf16* __restrict__ Bt0, const bf16* __restrict__ Bt1, const bf16* __restrict__ Bt2,
    TC* __restrict__ C0, TC* __restrict__ C1, TC* __restrict__ C2,
    const void* __restrict__ bias, int M, int N, int K, const int* __restrict__ flag)
{
    const int f32w = flag[0];
    const bf16* Bt = (blockIdx.z == 0) ? Bt0 : (blockIdx.z == 1 ? Bt1 : Bt2);
    TC* C = (blockIdx.z == 0) ? C0 : (blockIdx.z == 1 ? C1 : C2);

    const int tid = threadIdx.x;
    const int lane = tid & 63;
    const int w = tid >> 6;
    const int wm = w >> 1, wn = w & 1;
    const int bm = blockIdx.x * 128, bn = blockIdx.y * 128;
    const int rsub = lane & 15;
    const int ksub = (lane >> 4) * 8;

    const bf16* Abase = A + (size_t)(bm + wm * 64 + rsub) * K + ksub;
    const bf16* Bbase = Bt + (size_t)(bn + wn * 64 + rsub) * K + ksub;

    f32x4 acc[4][4];
#pragma unroll
    for (int i = 0; i < 4; ++i)
#pragma unroll
        for (int j = 0; j < 4; ++j) acc[i][j] = (f32x4){0.f, 0.f, 0.f, 0.f};

    for (int k0 = 0; k0 < K; k0 += 64) {
        bf16x8 av[2][4], bv[2][4];
#pragma unroll
        for (int kh = 0; kh < 2; ++kh) {
#pragma unroll
            for (int mi = 0; mi < 4; ++mi)
                av[kh][mi] = *(const bf16x8*)(Abase + (size_t)mi * 16 * K + k0 + kh * 32);
#pragma unroll
            for (int nj = 0; nj < 4; ++nj)
                bv[kh][nj] = *(const bf16x8*)(Bbase + (size_t)nj * 16 * K + k0 + kh * 32);
        }
#pragma unroll
        for (int kh = 0; kh < 2; ++kh)
#pragma unroll
            for (int mi = 0; mi < 4; ++mi)
#pragma unroll
                for (int nj = 0; nj < 4; ++nj)
                    acc[mi][nj] = __builtin_amdgcn_mfma_f32_16x16x32_bf16(
                        av[kh][mi], bv[kh][nj], acc[mi][nj], 0, 0, 0);
    }

    // C/D layout: col=lane&15, row=(lane>>4)*4+reg  [proven rounds 6/7]
#pragma unroll
    for (int mi = 0; mi < 4; ++mi) {
#pragma unroll
        for (int nj = 0; nj < 4; ++nj) {
            int c = bn + wn * 64 + nj * 16 + (lane & 15);
            float bia = bias ? ldin(bias, c, f32w) : 0.f;
#pragma unroll
            for (int r = 0; r < 4; ++r) {
                int row = bm + wm * 64 + mi * 16 + (lane >> 4) * 4 + r;
                float v = acc[mi][nj][r] + bia;
                if (ACT == 1) v = 0.5f * v * (1.0f + erff(v * 0.70710678118654752f));
                storev(C + (size_t)row * N + c, v);
            }
        }
    }
}

// ---------------------------------------------------------------------------
// Causal attention v2: one wave per (b,h,t) query row; 64-key tiles.
// Lane owns one KEY in the score phase (parallel dot via float4 K loads +
// LDS-broadcast q), then lane owns one DIM in PV (p broadcast via tiny LDS).
// Generic strides: in (sb,st,sh), out (ob,ot,oh). One exp/key, one wave
// reduce per TILE instead of per key.
// ---------------------------------------------------------------------------
template <typename TO>
__global__ __launch_bounds__(64) void attn_kernel2(
    const float* __restrict__ q, const float* __restrict__ k, const float* __restrict__ v,
    TO* __restrict__ o,
    int sb, int st, int sh, int ob, int ot, int oh)
{
    int t = blockIdx.x, hh = blockIdx.y, b = blockIdx.z;
    int lane = threadIdx.x;
    __shared__ float qs[64];
    __shared__ float ps[64];

    const size_t hb = (size_t)b * sb + (size_t)hh * sh;
    qs[lane] = q[hb + (size_t)t * st + lane];
    __syncthreads();

    float m = -1e30f, l = 0.f, acc = 0.f;
    for (int j0 = 0; j0 <= t; j0 += 64) {
        int jj = j0 + lane;
        bool valid = jj <= t;
        float s = -1e30f;
        if (valid) {
            const float* kr = k + hb + (size_t)jj * st;
            float sd = 0.f;
#pragma unroll
            for (int dd = 0; dd < 16; ++dd) {
                float4 k4 = *(const float4*)(kr + dd * 4);
                float4 q4 = *(const float4*)(qs + dd * 4);
                sd += k4.x * q4.x + k4.y * q4.y + k4.z * q4.z + k4.w * q4.w;
            }
            s = sd * 0.125f;  // 1/sqrt(64)
        }
        // tile max (once per 64 keys)
        float pm = s;
#pragma unroll
        for (int off = 32; off; off >>= 1) pm = fmaxf(pm, __shfl_xor(pm, off));
        float mn = fmaxf(m, pm);
        float corr = __expf(m - mn);
        float p = __expf(s - mn);  // 0 for invalid lanes (s=-1e30)
        float psum = p;
#pragma unroll
        for (int off = 32; off; off >>= 1) psum += __shfl_xor(psum, off);
        l = l * corr + psum;

        __syncthreads();          // prev tile's ps reads complete
        ps[lane] = p;
        __syncthreads();

        // PV: lane owns dim d=lane; p_j broadcast from LDS; V loads coalesced
        float a2 = 0.f;
        int jmax = min(64, t - j0 + 1);
        const float* vr = v + hb + (size_t)j0 * st + lane;
        for (int j = 0; j < jmax; ++j)
            a2 += ps[j] * vr[(size_t)j * st];
        acc = acc * corr + a2;
        m = mn;
    }
    storev(&o[(size_t)b * ob + (size_t)hh * oh + (size_t)t * ot + lane], acc / l);
}

// ---------------------------------------------------------------------------
// Level-1 projections + RoPE. One wave per (b,h,t). PROVEN (reads/writes
// head-major fp32, unchanged from rounds 2/6/7).
// ---------------------------------------------------------------------------
__global__ __launch_bounds__(64) void proj1_kernel(
    const float* __restrict__ o0,
    const void* __restrict__ Wq1, const void* __restrict__ Wk1, const void* __restrict__ Wv1,
    float* __restrict__ q1, float* __restrict__ k1, float* __restrict__ v1,
    const int* __restrict__ flag)
{
    const int f32w = flag[0];
    int t = blockIdx.x, hh = blockIdx.y, b = blockIdx.z;
    int lane = threadIdx.x;
    __shared__ float os[64];
    size_t rowoff = ((size_t)(b * CH + hh) * CT + t) * 64;
    os[lane] = o0[rowoff + lane];
    __syncthreads();

    size_t wbase = (size_t)hh * 64 * 64;
    float aq = 0.f, ak = 0.f, av = 0.f;
#pragma unroll 8
    for (int vv = 0; vv < 64; ++vv) {
        float ov = os[vv];
        aq += ov * ldin(Wq1, wbase + vv * 64 + lane, f32w);
        ak += ov * ldin(Wk1, wbase + vv * 64 + lane, f32w);
        av += ov * ldin(Wv1, wbase + vv * 64 + lane, f32w);
    }
    int i = lane >> 1;
    float inv = powf(10000.f, -(float)(2 * i) / 64.f);
    float ang = (float)t * inv;
    float sn, cs;
    sincosf(ang, &sn, &cs);
    float oq = __shfl_xor(aq, 1);
    float okk = __shfl_xor(ak, 1);
    float rq, rk;
    if (lane & 1) { rq = oq * sn + aq * cs; rk = okk * sn + ak * cs; }
    else          { rq = aq * cs - oq * sn; rk = ak * cs - okk * sn; }
    q1[rowoff + lane] = rq;
    k1[rowoff + lane] = rk;
    v1[rowoff + lane] = av;
}

// RoPE over ROW-MAJOR q0r and k0r [b*CT+t][h*64+d], thread per (b,t,h,pair)
__global__ __launch_bounds__(256) void rope_qk_rm_kernel(
    float* __restrict__ q, float* __restrict__ k)
{
    int idx = blockIdx.x * 256 + threadIdx.x;  // CB*CT*CH*32
    int i = idx & 31;
    int hh = (idx >> 5) & 7;
    int bt = idx >> 8;                          // b*CT + t
    int t = bt % CT;
    float inv = powf(10000.f, -(float)(2 * i) / 64.f);
    float ang = (float)t * inv;
    float sn, cs;
    sincosf(ang, &sn, &cs);
    size_t p = (size_t)bt * 512 + hh * 64 + 2 * i;
    float x1 = q[p], x2 = q[p + 1];
    q[p] = x1 * cs - x2 * sn;
    q[p + 1] = x1 * sn + x2 * cs;
    x1 = k[p]; x2 = k[p + 1];
    k[p] = x1 * cs - x2 * sn;
    k[p + 1] = x1 * sn + x2 * cs;
}

// toks = concat([state, x_seg, state]) -> bf16 (feeds MFMA A operand)
__global__ __launch_bounds__(256) void build_toks_kernel(
    const void* __restrict__ x, const float* __restrict__ state, bf16* __restrict__ toks,
    int seg, const int* __restrict__ flag)
{
    const int f32w = flag[0];
    int idx = blockIdx.x * 256 + threadIdx.x;  // B*T*D
    int d = idx & (CD - 1);
    int t = (idx >> 10) % CT;
    int b = idx / (CT * CD);
    float v;
    if (t < CST) v = state[(b * CST + t) * CD + d];
    else if (t < CST + CL) v = ldin(x, ((size_t)b * CS + seg * CL + (t - CST)) * CD + d, f32w);
    else v = state[(b * CST + (t - CST - CL)) * CD + d];
    toks[idx] = __float2bfloat16(v);
}

// split seg_out: middle L tokens -> a, last ST tokens -> state
__global__ __launch_bounds__(256) void seg_epi_kernel(
    const float* __restrict__ seg_out, float* __restrict__ a, float* __restrict__ state, int seg)
{
    int idx = blockIdx.x * 256 + threadIdx.x;  // B*(T-ST)*D
    int d = idx & (CD - 1);
    int tt = (idx >> 10) % (CT - CST);
    int b = idx / ((CT - CST) * CD);
    float v = seg_out[((size_t)b * CT + (tt + CST)) * CD + d];
    if (tt < CL) a[((size_t)b * CS + seg * CL + tt) * CD + d] = v;
    else state[(b * CST + (tt - CL)) * CD + d] = v;
}

__global__ __launch_bounds__(256) void init_state_kernel(
    const void* __restrict__ s0, float* __restrict__ state, const int* __restrict__ flag)
{
    const int f32w = flag[0];
    int idx = blockIdx.x * 256 + threadIdx.x;  // B*ST*D
    state[idx] = ldin(s0, idx % (CST * CD), f32w);
}

// LayerNorm(ra + x) * g + b.
__global__ __launch_bounds__(256) void ln_kernel(
    const float* __restrict__ ra, const void* __restrict__ x,
    const void* __restrict__ g, const void* __restrict__ bb,
    void* __restrict__ outp, int out_ext, const int* __restrict__ flag)
{
    const int f32w = flag[0];
    int row = blockIdx.x;
    int tid = threadIdx.x;
    __shared__ float buf[CD];
    __shared__ float red[4];

    float s = 0.f;
    for (int c = tid; c < CD; c += 256) {
        float v = ra[(size_t)row * CD + c] + ldin(x, (size_t)row * CD + c, f32w);
        buf[c] = v;
        s += v;
    }
#pragma unroll
    for (int off = 32; off; off >>= 1) s += __shfl_xor(s, off);
    if ((tid & 63) == 0) red[tid >> 6] = s;
    __syncthreads();
    float mu = (red[0] + red[1] + red[2] + red[3]) * (1.f / CD);
    __syncthreads();

    float vs = 0.f;
    for (int c = tid; c < CD; c += 256) {
        float d0 = buf[c] - mu;
        vs += d0 * d0;
    }
#pragma unroll
    for (int off = 32; off; off >>= 1) vs += __shfl_xor(vs, off);
    if ((tid & 63) == 0) red[tid >> 6] = vs;
    __syncthreads();
    float var = (red[0] + red[1] + red[2] + red[3]) * (1.f / CD);
    float rs = rsqrtf(var + 1e-5f);

    for (int c = tid; c < CD; c += 256) {
        float y = (buf[c] - mu) * rs * ldin(g, c, f32w) + ldin(bb, c, f32w);
        size_t idx = (size_t)row * CD + c;
        if (!out_ext) {
            ((bf16*)outp)[idx] = __float2bfloat16(y);
        } else if (f32w) {
            ((float*)outp)[idx] = y;
        } else {
            ((bf16*)outp)[idx] = __float2bfloat16(y);
        }
    }
}

extern "C" void kernel_launch(void* const* d_in, const int* in_sizes, int n_in,
                              void* d_out, int out_size, void* d_ws, size_t ws_size,
                              hipStream_t stream)
{
    const void* x      = d_in[0];
    const void* s0     = d_in[1];
    const void* Wq0    = d_in[2];
    const void* Wk0    = d_in[3];
    const void* Wv0    = d_in[4];
    const void* Wq1    = d_in[5];
    const void* Wk1    = d_in[6];
    const void* Wv1    = d_in[7];
    const void* Wo     = d_in[8];
    const void* bo     = d_in[9];
    const void* g_attn = d_in[10];
    const void* b_attn = d_in[11];
    const void* W1     = d_in[12];
    const void* b1     = d_in[13];
    const void* W2     = d_in[14];
    const void* b2     = d_in[15];
    const void* g_mlp  = d_in[16];
    const void* b_mlp  = d_in[17];

    // workspace slot layout BYTE-IDENTICAL to passing rounds 2/6/7 (~90.7 MB);
    // interiors repurposed where dtype/layout changed (always <= slot size).
    int* flag = (int*)d_ws;
    float* f = (float*)((char*)d_ws + 16);
    float* toks_slot = f; f += (size_t)CB * CT * CD;       // bf16 toks (half used)
    float* q0 = f;      f += (size_t)CB * CH * CT * 64;    // row-major q0r [1280][512]
    float* k0 = f;      f += (size_t)CB * CH * CT * 64;    // row-major k0r
    float* v0 = f;      f += (size_t)CB * CH * CT * 64;    // row-major v0r
    float* o0 = f;      f += (size_t)CB * CH * CT * 64;    // head-major (proj1 input)
    float* q1 = f;      f += (size_t)CB * CH * CT * 64;    // head-major
    float* k1 = f;      f += (size_t)CB * CH * CT * 64;
    float* v1 = f;      f += (size_t)CB * CH * CT * 64;
    float* o1t_slot = f; f += (size_t)CB * CT * (CH * 64); // bf16 o1t [1280][512] (half used)
    float* seg_out = f; f += (size_t)CB * CT * CD;         // fp32 row-major [1280][1024]
    float* state = f;   f += (size_t)CB * CST * CD;
    float* a = f;       f += (size_t)CB * CS * CD;
    bf16* h = (bf16*)f;                                    // LN1 out [B*S, D] bf16
    bf16* g1 = h + (size_t)CB * CS * CD;                   // MLP mid chunk [MCH, DH] bf16

    bf16* toks = (bf16*)toks_slot;
    bf16* o1t  = (bf16*)o1t_slot;
    // QKV/Wo transposed weights live in the h region (dead until LN1 -> by
    // then they are no longer needed). 4 x 1 MB << 16.8 MB slot.
    bf16* WtQ = h;                                         // [512][1024]
    bf16* WtK = WtQ + (size_t)512 * 1024;
    bf16* WtV = WtK + (size_t)512 * 1024;
    bf16* WtO = WtV + (size_t)512 * 1024;                  // [1024][512]
    // MLP transposed weights in toks region (dead during MLP; proven round 7)
    bf16* Wt1 = (bf16*)toks_slot;                          // [CDH][CD]  8.39 MB
    bf16* Wt2 = Wt1 + (size_t)CDH * CD;                    // [CD][CDH]  (16.8 MB < 32 MB dead)

    sniff_kernel<<<1, 64, 0, stream>>>(x, flag);
    init_state_kernel<<<(CB * CST * CD) / 256, 256, 0, stream>>>(s0, state, flag);

    // pre-transpose attention weights into h region
    transpose_kernel<<<dim3(8, 16), 256, 0, stream>>>(Wq0, WtQ, CD, 512, flag);
    transpose_kernel<<<dim3(8, 16), 256, 0, stream>>>(Wk0, WtK, CD, 512, flag);
    transpose_kernel<<<dim3(8, 16), 256, 0, stream>>>(Wv0, WtV, CD, 512, flag);
    transpose_kernel<<<dim3(16, 8), 256, 0, stream>>>(Wo, WtO, 512, CD, flag);

    for (int seg = 0; seg < NSEG; ++seg) {
        build_toks_kernel<<<(CB * CT * CD) / 256, 256, 0, stream>>>(x, state, toks, seg, flag);
        // q0r,k0r,v0r = toks @ {Wq0,Wk0,Wv0}, row-major [1280][512]
        mfma_nt<float, 0><<<dim3(10, 4, 3), 256, 0, stream>>>(
            toks, WtQ, WtK, WtV, q0, k0, v0, nullptr, CB * CT, 512, CD, flag);
        rope_qk_rm_kernel<<<(CB * CT * CH * 32) / 256, 256, 0, stream>>>(q0, k0);
        // attn1: row-major qkv in, head-major o0 out
        attn_kernel2<float><<<dim3(CT, CH, CB), 64, 0, stream>>>(
            q0, k0, v0, o0,
            CT * 512, 512, 64,              // in: sb, st, sh (row-major)
            CH * CT * 64, 64, CT * 64);     // out: ob, ot, oh (head-major)
        proj1_kernel<<<dim3(CT, CH, CB), 64, 0, stream>>>(o0, Wq1, Wk1, Wv1, q1, k1, v1, flag);
        // attn2: head-major q1/k1/v1 in, token-major bf16 o1t out [1280][512]
        attn_kernel2<bf16><<<dim3(CT, CH, CB), 64, 0, stream>>>(
            q1, k1, v1, o1t,
            CH * CT * 64, 64, CT * 64,      // in: sb, st, sh (head-major)
            CT * 512, 512, 64);             // out: ob, ot, oh (token-major)
        // seg_out = o1t @ Wo + bo  (M=1280, N=1024, K=512)
        mfma_nt<float, 0><<<dim3(10, 8, 1), 256, 0, stream>>>(
            o1t, WtO, WtO, WtO, seg_out, seg_out, seg_out, bo, CB * CT, CD, 512, flag);
        seg_epi_kernel<<<(CB * (CT - CST) * CD) / 256, 256, 0, stream>>>(seg_out, a, state, seg);
    }

    // h = LN(a + x) -> bf16 internal (overwrites WtQ..WtO — dead by now)
    ln_kernel<<<CB * CS, 256, 0, stream>>>(a, x, g_attn, b_attn, h, 0, flag);

    // transpose MLP weights into the now-dead segment region (proven round 7)
    transpose_kernel<<<dim3(CDH / 64, CD / 64), 256, 0, stream>>>(W1, Wt1, CD, CDH, flag);
    transpose_kernel<<<dim3(CD / 64, CDH / 64), 256, 0, stream>>>(W2, Wt2, CDH, CD, flag);

    // MLP in M-chunks of 1024 rows (proven round 7)
    for (int c = 0; c < (CB * CS) / MCH; ++c) {
        mfma_nt<bf16, 1><<<dim3(MCH / 128, CDH / 128, 1), 256, 0, stream>>>(
            h + (size_t)c * MCH * CD, Wt1, Wt1, Wt1, g1, g1, g1, b1, MCH, CDH, CD, flag);
        mfma_nt<float, 0><<<dim3(MCH / 128, CD / 128, 1), 256, 0, stream>>>(
            g1, Wt2, Wt2, Wt2, a + (size_t)c * MCH * CD, a, a, b2, MCH, CD, CDH, flag);
    }
    // out = LN(m + x) -> flagged external dtype
    ln_kernel<<<CB * CS, 256, 0, stream>>>(a, x, g_mlp, b_mlp, d_out, 1, flag);
}

// Round 9
// 3096.216 us; speedup vs baseline: 5.0462x; 1.4232x over previous
//
#include <hip/hip_runtime.h>
#include <hip/hip_bf16.h>

typedef __hip_bfloat16 bf16;
typedef short bf16x8 __attribute__((ext_vector_type(8)));   // 8 bf16 = 4 VGPRs
typedef float f32x4 __attribute__((ext_vector_type(4)));

// Problem constants
#define CB 2
#define CS 4096
#define CD 1024
#define CL 512
#define CST 64
#define CH 8
#define CT 640      // 2*ST + L
#define CDH 4096
#define NSEG 8
#define MCH 1024    // MLP M-chunk rows

__device__ __forceinline__ float tof(float x) { return x; }
__device__ __forceinline__ float tof(bf16 x) { return __bfloat162float(x); }
__device__ __forceinline__ void storev(float* p, float v) { *p = v; }
__device__ __forceinline__ void storev(bf16* p, float v) { *p = __float2bfloat16(v); }

// runtime-dtype input load: f32w!=0 -> buffer is float32, else bf16
__device__ __forceinline__ float ldin(const void* p, size_t i, int f32w) {
    if (f32w) return ((const float*)p)[i];
    return __bfloat162float(((const bf16*)p)[i]);
}

// ---------------------------------------------------------------------------
// Dtype sniffer (proven rounds 2/6/7/8; resolves flag=0 = bf16 here).
// ---------------------------------------------------------------------------
__global__ void sniff_kernel(const void* x, int* flag) {
    if (threadIdx.x == 0 && blockIdx.x == 0) {
        const bf16* hb = (const bf16*)x;
        int plaus = 0;
        for (int i = 0; i < 256; ++i) {
            float v = __bfloat162float(hb[2 * i]);
            float a = fabsf(v);
            if (v == 0.f || (a > 1e-4f && a < 100.f)) ++plaus;
        }
        flag[0] = (plaus < 128) ? 1 : 0;
    }
}

// ---------------------------------------------------------------------------
// bf16 transpose: out[C][R] = in[R][C], 64x64 tiles. PROVEN rounds 7/8.
// ---------------------------------------------------------------------------
__global__ __launch_bounds__(256) void transpose_kernel(
    const void* __restrict__ in, bf16* __restrict__ out, int R, int C,
    const int* __restrict__ flag)
{
    const int f32w = flag[0];
    __shared__ short t[64][72];
    int tid = threadIdx.x;
    int c0 = blockIdx.x * 64, r0 = blockIdx.y * 64;
    int cc = tid & 63, rr = tid >> 6;
#pragma unroll
    for (int i = 0; i < 16; ++i) {
        bf16 v = __float2bfloat16(ldin(in, (size_t)(r0 + rr + i * 4) * C + c0 + cc, f32w));
        t[rr + i * 4][cc] = *(short*)&v;
    }
    __syncthreads();
#pragma unroll
    for (int i = 0; i < 16; ++i)
        ((short*)out)[(size_t)(c0 + rr + i * 4) * R + r0 + cc] = t[cc][rr + i * 4];
}

// ---------------------------------------------------------------------------
// MFMA GEMM (PROVEN rounds 7/8), now with OUTM template:
//   OUTM=0: row-major C (proven path, unchanged code)
//   OUTM=1: Wo epilogue split — row (b,t): t<ST discard; t<ST+L -> C0 = a
//           (indexed by seg); else -> C1 = state.
// C[M,N] = A[M,K](bf16) * Bt[N,K]^T(bf16). 4 waves (2x2), 128x128, no LDS.
// ---------------------------------------------------------------------------
template <typename TC, int ACT, int OUTM>
__global__ __launch_bounds__(256) void mfma_nt(
    const bf16* __restrict__ A,
    const bf16* __restrict__ Bt0, const bf16* __restrict__ Bt1, const bf16* __restrict__ Bt2,
    TC* __restrict__ C0, TC* __restrict__ C1, TC* __restrict__ C2,
    const void* __restrict__ bias, int M, int N, int K, int seg,
    const int* __restrict__ flag)
{
    const int f32w = flag[0];
    const bf16* Bt = (blockIdx.z == 0) ? Bt0 : (blockIdx.z == 1 ? Bt1 : Bt2);
    TC* C = (blockIdx.z == 0) ? C0 : (blockIdx.z == 1 ? C1 : C2);

    const int tid = threadIdx.x;
    const int lane = tid & 63;
    const int w = tid >> 6;
    const int wm = w >> 1, wn = w & 1;
    const int bm = blockIdx.x * 128, bn = blockIdx.y * 128;
    const int rsub = lane & 15;
    const int ksub = (lane >> 4) * 8;

    const bf16* Abase = A + (size_t)(bm + wm * 64 + rsub) * K + ksub;
    const bf16* Bbase = Bt + (size_t)(bn + wn * 64 + rsub) * K + ksub;

    f32x4 acc[4][4];
#pragma unroll
    for (int i = 0; i < 4; ++i)
#pragma unroll
        for (int j = 0; j < 4; ++j) acc[i][j] = (f32x4){0.f, 0.f, 0.f, 0.f};

    for (int k0 = 0; k0 < K; k0 += 64) {
        bf16x8 av[2][4], bv[2][4];
#pragma unroll
        for (int kh = 0; kh < 2; ++kh) {
#pragma unroll
            for (int mi = 0; mi < 4; ++mi)
                av[kh][mi] = *(const bf16x8*)(Abase + (size_t)mi * 16 * K + k0 + kh * 32);
#pragma unroll
            for (int nj = 0; nj < 4; ++nj)
                bv[kh][nj] = *(const bf16x8*)(Bbase + (size_t)nj * 16 * K + k0 + kh * 32);
        }
#pragma unroll
        for (int kh = 0; kh < 2; ++kh)
#pragma unroll
            for (int mi = 0; mi < 4; ++mi)
#pragma unroll
                for (int nj = 0; nj < 4; ++nj)
                    acc[mi][nj] = __builtin_amdgcn_mfma_f32_16x16x32_bf16(
                        av[kh][mi], bv[kh][nj], acc[mi][nj], 0, 0, 0);
    }

    // C/D layout: col=lane&15, row=(lane>>4)*4+reg  [proven rounds 6/7/8]
#pragma unroll
    for (int mi = 0; mi < 4; ++mi) {
#pragma unroll
        for (int nj = 0; nj < 4; ++nj) {
            int c = bn + wn * 64 + nj * 16 + (lane & 15);
            float bia = bias ? ldin(bias, c, f32w) : 0.f;
#pragma unroll
            for (int r = 0; r < 4; ++r) {
                int row = bm + wm * 64 + mi * 16 + (lane >> 4) * 4 + r;
                float v = acc[mi][nj][r] + bia;
                if (ACT == 1) v = 0.5f * v * (1.0f + erff(v * 0.70710678118654752f));
                if (OUTM == 0) {
                    storev(C + (size_t)row * N + c, v);
                } else {
                    int bb2 = row / CT, t = row % CT;
                    if (t >= CST) {
                        if (t < CST + CL)
                            storev(C0 + ((size_t)bb2 * CS + (size_t)seg * CL + (t - CST)) * CD + c, v);
                        else
                            storev(C1 + ((size_t)bb2 * CST + (t - CST - CL)) * CD + c, v);
                    }
                }
            }
        }
    }
}

// ---------------------------------------------------------------------------
// Causal attention v3: one wave per (b,h, 4 query rows t0..t0+3).
// Score: lane owns KEY (K row loaded once, serves 4 queries -> 4 indep chains).
// PV: lane owns DIM; fixed-64 fully-unrolled loop, p via float4 LDS broadcast,
// 8 independent accumulator chains. Invalid lanes contribute p=0.
// FUSE=1: epilogue applies proj1 (o0 @ Wq1/Wk1/Wv1 per head) + RoPE and
// writes q1/k1/v1 (head-major) instead of storing o.
// ---------------------------------------------------------------------------
template <typename TO, int FUSE>
__global__ __launch_bounds__(64) void attn_kernel3(
    const float* __restrict__ q, const float* __restrict__ k, const float* __restrict__ v,
    TO* __restrict__ o,
    int sb, int st, int sh, int ob, int ot, int oh,
    const void* __restrict__ Wq1, const void* __restrict__ Wk1, const void* __restrict__ Wv1,
    float* __restrict__ q1o, float* __restrict__ k1o, float* __restrict__ v1o,
    const int* __restrict__ flag)
{
    int t0 = blockIdx.x * 4, hh = blockIdx.y, b = blockIdx.z;
    int lane = threadIdx.x;
    __shared__ float qs[4][64];
    __shared__ float ps[4][64];

    const size_t hb = (size_t)b * sb + (size_t)hh * sh;
#pragma unroll
    for (int qi = 0; qi < 4; ++qi)
        qs[qi][lane] = q[hb + (size_t)(t0 + qi) * st + lane];
    __syncthreads();

    float m[4], l[4], acc[4];
#pragma unroll
    for (int qi = 0; qi < 4; ++qi) { m[qi] = -1e30f; l[qi] = 0.f; acc[qi] = 0.f; }

    const int tmax = t0 + 3;
    for (int j0 = 0; j0 <= tmax; j0 += 64) {
        int jj = j0 + lane;
        float sd[4] = {0.f, 0.f, 0.f, 0.f};
        if (jj <= tmax) {
            const float* kr = k + hb + (size_t)jj * st;
#pragma unroll
            for (int dd = 0; dd < 16; ++dd) {
                float4 k4 = *(const float4*)(kr + dd * 4);
#pragma unroll
                for (int qi = 0; qi < 4; ++qi) {
                    float4 q4 = *(const float4*)(&qs[qi][dd * 4]);
                    sd[qi] += k4.x * q4.x + k4.y * q4.y + k4.z * q4.z + k4.w * q4.w;
                }
            }
        }
        float corr[4], pnew[4];
#pragma unroll
        for (int qi = 0; qi < 4; ++qi) {
            float s = (jj <= t0 + qi) ? sd[qi] * 0.125f : -1e30f;
            float pm = s;
#pragma unroll
            for (int off = 32; off; off >>= 1) pm = fmaxf(pm, __shfl_xor(pm, off));
            float mn = fmaxf(m[qi], pm);
            corr[qi] = __expf(m[qi] - mn);
            float p = __expf(s - mn);
            float psum = p;
#pragma unroll
            for (int off = 32; off; off >>= 1) psum += __shfl_xor(psum, off);
            l[qi] = l[qi] * corr[qi] + psum;
            m[qi] = mn;
            pnew[qi] = p;
        }
        __syncthreads();
#pragma unroll
        for (int qi = 0; qi < 4; ++qi) ps[qi][lane] = pnew[qi];
        __syncthreads();

        // PV: fixed 64 keys (p=0 beyond valid); V rows j0+j <= 639 in-bounds.
        float a2a[4] = {0.f, 0.f, 0.f, 0.f}, a2b[4] = {0.f, 0.f, 0.f, 0.f};
        const float* vr = v + hb + (size_t)j0 * st + lane;
#pragma unroll
        for (int j4 = 0; j4 < 64; j4 += 8) {
            float vv[8];
#pragma unroll
            for (int u = 0; u < 8; ++u) vv[u] = vr[(size_t)(j4 + u) * st];
#pragma unroll
            for (int qi = 0; qi < 4; ++qi) {
                float4 pa = *(const float4*)&ps[qi][j4];
                float4 pb = *(const float4*)&ps[qi][j4 + 4];
                a2a[qi] += pa.x * vv[0] + pa.y * vv[1] + pa.z * vv[2] + pa.w * vv[3];
                a2b[qi] += pb.x * vv[4] + pb.y * vv[5] + pb.z * vv[6] + pb.w * vv[7];
            }
        }
#pragma unroll
        for (int qi = 0; qi < 4; ++qi) acc[qi] = acc[qi] * corr[qi] + a2a[qi] + a2b[qi];
    }

    if (FUSE == 0) {
#pragma unroll
        for (int qi = 0; qi < 4; ++qi)
            storev(&o[(size_t)b * ob + (size_t)hh * oh + (size_t)(t0 + qi) * ot + lane],
                   acc[qi] / l[qi]);
    } else {
        const int f32w = flag[0];
        __syncthreads();
#pragma unroll
        for (int qi = 0; qi < 4; ++qi) qs[qi][lane] = acc[qi] / l[qi];  // reuse qs as os
        __syncthreads();
        size_t wb = (size_t)hh * 4096;
        float aq[4] = {0.f, 0.f, 0.f, 0.f}, ak[4] = {0.f, 0.f, 0.f, 0.f},
              av[4] = {0.f, 0.f, 0.f, 0.f};
#pragma unroll 8
        for (int vv = 0; vv < 64; ++vv) {
            float wq = ldin(Wq1, wb + vv * 64 + lane, f32w);
            float wk = ldin(Wk1, wb + vv * 64 + lane, f32w);
            float wv = ldin(Wv1, wb + vv * 64 + lane, f32w);
#pragma unroll
            for (int qi = 0; qi < 4; ++qi) {
                float ov = qs[qi][vv];
                aq[qi] += ov * wq; ak[qi] += ov * wk; av[qi] += ov * wv;
            }
        }
        int i = lane >> 1;
        float inv = powf(10000.f, -(float)(2 * i) / 64.f);
#pragma unroll
        for (int qi = 0; qi < 4; ++qi) {
            int t = t0 + qi;
            float ang = (float)t * inv;
            float sn, cs;
            sincosf(ang, &sn, &cs);
            float oq = __shfl_xor(aq[qi], 1);
            float ok = __shfl_xor(ak[qi], 1);
            float rq, rk;
            if (lane & 1) { rq = oq * sn + aq[qi] * cs; rk = ok * sn + ak[qi] * cs; }
            else          { rq = aq[qi] * cs - oq * sn; rk = ak[qi] * cs - ok * sn; }
            size_t rowoff = ((size_t)(b * CH + hh) * CT + t) * 64;
            q1o[rowoff + lane] = rq;
            k1o[rowoff + lane] = rk;
            v1o[rowoff + lane] = av[qi];
        }
    }
}

// RoPE over ROW-MAJOR q0r and k0r [b*CT+t][h*64+d], thread per (b,t,h,pair)
__global__ __launch_bounds__(256) void rope_qk_rm_kernel(
    float* __restrict__ q, float* __restrict__ k)
{
    int idx = blockIdx.x * 256 + threadIdx.x;  // CB*CT*CH*32
    int i = idx & 31;
    int hh = (idx >> 5) & 7;
    int bt = idx >> 8;                          // b*CT + t
    int t = bt % CT;
    float inv = powf(10000.f, -(float)(2 * i) / 64.f);
    float ang = (float)t * inv;
    float sn, cs;
    sincosf(ang, &sn, &cs);
    size_t p = (size_t)bt * 512 + hh * 64 + 2 * i;
    float x1 = q[p], x2 = q[p + 1];
    q[p] = x1 * cs - x2 * sn;
    q[p + 1] = x1 * sn + x2 * cs;
    x1 = k[p]; x2 = k[p + 1];
    k[p] = x1 * cs - x2 * sn;
    k[p + 1] = x1 * sn + x2 * cs;
}

// toks = concat([state, x_seg, state]) -> bf16 (feeds MFMA A operand)
__global__ __launch_bounds__(256) void build_toks_kernel(
    const void* __restrict__ x, const float* __restrict__ state, bf16* __restrict__ toks,
    int seg, const int* __restrict__ flag)
{
    const int f32w = flag[0];
    int idx = blockIdx.x * 256 + threadIdx.x;  // B*T*D
    int d = idx & (CD - 1);
    int t = (idx >> 10) % CT;
    int b = idx / (CT * CD);
    float v;
    if (t < CST) v = state[(b * CST + t) * CD + d];
    else if (t < CST + CL) v = ldin(x, ((size_t)b * CS + seg * CL + (t - CST)) * CD + d, f32w);
    else v = state[(b * CST + (t - CST - CL)) * CD + d];
    toks[idx] = __float2bfloat16(v);
}

__global__ __launch_bounds__(256) void init_state_kernel(
    const void* __restrict__ s0, float* __restrict__ state, const int* __restrict__ flag)
{
    const int f32w = flag[0];
    int idx = blockIdx.x * 256 + threadIdx.x;  // B*ST*D
    state[idx] = ldin(s0, idx % (CST * CD), f32w);
}

// LayerNorm(ra + x) * g + b.
__global__ __launch_bounds__(256) void ln_kernel(
    const float* __restrict__ ra, const void* __restrict__ x,
    const void* __restrict__ g, const void* __restrict__ bb,
    void* __restrict__ outp, int out_ext, const int* __restrict__ flag)
{
    const int f32w = flag[0];
    int row = blockIdx.x;
    int tid = threadIdx.x;
    __shared__ float buf[CD];
    __shared__ float red[4];

    float s = 0.f;
    for (int c = tid; c < CD; c += 256) {
        float v = ra[(size_t)row * CD + c] + ldin(x, (size_t)row * CD + c, f32w);
        buf[c] = v;
        s += v;
    }
#pragma unroll
    for (int off = 32; off; off >>= 1) s += __shfl_xor(s, off);
    if ((tid & 63) == 0) red[tid >> 6] = s;
    __syncthreads();
    float mu = (red[0] + red[1] + red[2] + red[3]) * (1.f / CD);
    __syncthreads();

    float vs = 0.f;
    for (int c = tid; c < CD; c += 256) {
        float d0 = buf[c] - mu;
        vs += d0 * d0;
    }
#pragma unroll
    for (int off = 32; off; off >>= 1) vs += __shfl_xor(vs, off);
    if ((tid & 63) == 0) red[tid >> 6] = vs;
    __syncthreads();
    float var = (red[0] + red[1] + red[2] + red[3]) * (1.f / CD);
    float rs = rsqrtf(var + 1e-5f);

    for (int c = tid; c < CD; c += 256) {
        float y = (buf[c] - mu) * rs * ldin(g, c, f32w) + ldin(bb, c, f32w);
        size_t idx = (size_t)row * CD + c;
        if (!out_ext) {
            ((bf16*)outp)[idx] = __float2bfloat16(y);
        } else if (f32w) {
            ((float*)outp)[idx] = y;
        } else {
            ((bf16*)outp)[idx] = __float2bfloat16(y);
        }
    }
}

extern "C" void kernel_launch(void* const* d_in, const int* in_sizes, int n_in,
                              void* d_out, int out_size, void* d_ws, size_t ws_size,
                              hipStream_t stream)
{
    const void* x      = d_in[0];
    const void* s0     = d_in[1];
    const void* Wq0    = d_in[2];
    const void* Wk0    = d_in[3];
    const void* Wv0    = d_in[4];
    const void* Wq1    = d_in[5];
    const void* Wk1    = d_in[6];
    const void* Wv1    = d_in[7];
    const void* Wo     = d_in[8];
    const void* bo     = d_in[9];
    const void* g_attn = d_in[10];
    const void* b_attn = d_in[11];
    const void* W1     = d_in[12];
    const void* b1     = d_in[13];
    const void* W2     = d_in[14];
    const void* b2     = d_in[15];
    const void* g_mlp  = d_in[16];
    const void* b_mlp  = d_in[17];

    // workspace slot layout BYTE-IDENTICAL to passing rounds 2/6/7/8 (~90.7 MB)
    int* flag = (int*)d_ws;
    float* f = (float*)((char*)d_ws + 16);
    float* toks_slot = f; f += (size_t)CB * CT * CD;       // bf16 toks
    float* q0 = f;      f += (size_t)CB * CH * CT * 64;    // row-major q0r [1280][512]
    float* k0 = f;      f += (size_t)CB * CH * CT * 64;
    float* v0 = f;      f += (size_t)CB * CH * CT * 64;
    float* o0 = f;      f += (size_t)CB * CH * CT * 64;    // (unused now)
    float* q1 = f;      f += (size_t)CB * CH * CT * 64;    // head-major
    float* k1 = f;      f += (size_t)CB * CH * CT * 64;
    float* v1 = f;      f += (size_t)CB * CH * CT * 64;
    float* o1t_slot = f; f += (size_t)CB * CT * (CH * 64); // bf16 o1t [1280][512]
    float* seg_out = f; f += (size_t)CB * CT * CD;         // (unused now)
    float* state = f;   f += (size_t)CB * CST * CD;
    float* a = f;       f += (size_t)CB * CS * CD;
    bf16* h = (bf16*)f;                                    // LN1 out [B*S, D] bf16
    bf16* g1 = h + (size_t)CB * CS * CD;                   // MLP mid chunk [MCH, DH] bf16

    bf16* toks = (bf16*)toks_slot;
    bf16* o1t  = (bf16*)o1t_slot;
    bf16* WtQ = h;                                         // h region dead until LN1
    bf16* WtK = WtQ + (size_t)512 * 1024;
    bf16* WtV = WtK + (size_t)512 * 1024;
    bf16* WtO = WtV + (size_t)512 * 1024;                  // [1024][512]
    bf16* Wt1 = (bf16*)toks_slot;                          // seg region dead during MLP
    bf16* Wt2 = Wt1 + (size_t)CDH * CD;

    sniff_kernel<<<1, 64, 0, stream>>>(x, flag);
    init_state_kernel<<<(CB * CST * CD) / 256, 256, 0, stream>>>(s0, state, flag);

    transpose_kernel<<<dim3(8, 16), 256, 0, stream>>>(Wq0, WtQ, CD, 512, flag);
    transpose_kernel<<<dim3(8, 16), 256, 0, stream>>>(Wk0, WtK, CD, 512, flag);
    transpose_kernel<<<dim3(8, 16), 256, 0, stream>>>(Wv0, WtV, CD, 512, flag);
    transpose_kernel<<<dim3(16, 8), 256, 0, stream>>>(Wo, WtO, 512, CD, flag);

    for (int seg = 0; seg < NSEG; ++seg) {
        build_toks_kernel<<<(CB * CT * CD) / 256, 256, 0, stream>>>(x, state, toks, seg, flag);
        // q0r,k0r,v0r = toks @ {Wq0,Wk0,Wv0}, row-major [1280][512]
        mfma_nt<float, 0, 0><<<dim3(10, 4, 3), 256, 0, stream>>>(
            toks, WtQ, WtK, WtV, q0, k0, v0, nullptr, CB * CT, 512, CD, 0, flag);
        rope_qk_rm_kernel<<<(CB * CT * CH * 32) / 256, 256, 0, stream>>>(q0, k0);
        // attn1 (row-major in) fused with proj1+RoPE -> q1/k1/v1 head-major
        attn_kernel3<float, 1><<<dim3(CT / 4, CH, CB), 64, 0, stream>>>(
            q0, k0, v0, o0,
            CT * 512, 512, 64, 0, 0, 0,
            Wq1, Wk1, Wv1, q1, k1, v1, flag);
        // attn2 (head-major in) -> token-major bf16 o1t [1280][512]
        attn_kernel3<bf16, 0><<<dim3(CT / 4, CH, CB), 64, 0, stream>>>(
            q1, k1, v1, o1t,
            CH * CT * 64, 64, CT * 64, CT * 512, 512, 64,
            nullptr, nullptr, nullptr, nullptr, nullptr, nullptr, flag);
        // Wo GEMM with fused epilogue split: middle L rows -> a, last ST -> state
        mfma_nt<float, 0, 1><<<dim3(10, 8, 1), 256, 0, stream>>>(
            o1t, WtO, WtO, WtO, a, state, a, bo, CB * CT, CD, 512, seg, flag);
    }

    // h = LN(a + x) -> bf16 internal (overwrites WtQ..WtO — dead by now)
    ln_kernel<<<CB * CS, 256, 0, stream>>>(a, x, g_attn, b_attn, h, 0, flag);

    transpose_kernel<<<dim3(CDH / 64, CD / 64), 256, 0, stream>>>(W1, Wt1, CD, CDH, flag);
    transpose_kernel<<<dim3(CD / 64, CDH / 64), 256, 0, stream>>>(W2, Wt2, CDH, CD, flag);

    for (int c = 0; c < (CB * CS) / MCH; ++c) {
        mfma_nt<bf16, 1, 0><<<dim3(MCH / 128, CDH / 128, 1), 256, 0, stream>>>(
            h + (size_t)c * MCH * CD, Wt1, Wt1, Wt1, g1, g1, g1, b1, MCH, CDH, CD, 0, flag);
        mfma_nt<float, 0, 0><<<dim3(MCH / 128, CD / 128, 1), 256, 0, stream>>>(
            g1, Wt2, Wt2, Wt2, a + (size_t)c * MCH * CD, a, a, b2, MCH, CD, CDH, 0, flag);
    }
    ln_kernel<<<CB * CS, 256, 0, stream>>>(a, x, g_mlp, b_mlp, d_out, 1, flag);
}

// Round 10
// 2378.825 us; speedup vs baseline: 6.5680x; 1.3016x over previous
//
#include <hip/hip_runtime.h>
#include <hip/hip_bf16.h>

typedef __hip_bfloat16 bf16;
typedef short bf16x8 __attribute__((ext_vector_type(8)));   // 8 bf16 = 4 VGPRs
typedef float f32x4 __attribute__((ext_vector_type(4)));

// Problem constants
#define CB 2
#define CS 4096
#define CD 1024
#define CL 512
#define CST 64
#define CH 8
#define CT 640      // 2*ST + L
#define CDH 4096
#define NSEG 8
#define MCH 1024    // MLP M-chunk rows

__device__ __forceinline__ float tof(float x) { return x; }
__device__ __forceinline__ float tof(bf16 x) { return __bfloat162float(x); }
__device__ __forceinline__ void storev(float* p, float v) { *p = v; }
__device__ __forceinline__ void storev(bf16* p, float v) { *p = __float2bfloat16(v); }

// runtime-dtype input load: f32w!=0 -> buffer is float32, else bf16
__device__ __forceinline__ float ldin(const void* p, size_t i, int f32w) {
    if (f32w) return ((const float*)p)[i];
    return __bfloat162float(((const bf16*)p)[i]);
}

// ---------------------------------------------------------------------------
// Dtype sniffer (proven rounds 2/6/7/8/9; resolves flag=0 = bf16 here).
// ---------------------------------------------------------------------------
__global__ void sniff_kernel(const void* x, int* flag) {
    if (threadIdx.x == 0 && blockIdx.x == 0) {
        const bf16* hb = (const bf16*)x;
        int plaus = 0;
        for (int i = 0; i < 256; ++i) {
            float v = __bfloat162float(hb[2 * i]);
            float a = fabsf(v);
            if (v == 0.f || (a > 1e-4f && a < 100.f)) ++plaus;
        }
        flag[0] = (plaus < 128) ? 1 : 0;
    }
}

// ---------------------------------------------------------------------------
// bf16 transpose: out[C][R] = in[R][C], 64x64 tiles. PROVEN rounds 7/8/9.
// ---------------------------------------------------------------------------
__global__ __launch_bounds__(256) void transpose_kernel(
    const void* __restrict__ in, bf16* __restrict__ out, int R, int C,
    const int* __restrict__ flag)
{
    const int f32w = flag[0];
    __shared__ short t[64][72];
    int tid = threadIdx.x;
    int c0 = blockIdx.x * 64, r0 = blockIdx.y * 64;
    int cc = tid & 63, rr = tid >> 6;
#pragma unroll
    for (int i = 0; i < 16; ++i) {
        bf16 v = __float2bfloat16(ldin(in, (size_t)(r0 + rr + i * 4) * C + c0 + cc, f32w));
        t[rr + i * 4][cc] = *(short*)&v;
    }
    __syncthreads();
#pragma unroll
    for (int i = 0; i < 16; ++i)
        ((short*)out)[(size_t)(c0 + rr + i * 4) * R + r0 + cc] = t[cc][rr + i * 4];
}

// ---------------------------------------------------------------------------
// MFMA GEMM with register-staged LINEAR LDS (this round's experiment).
// Same shapes/epilogue/select as the proven round-9 mfma_nt; only the
// fragment sourcing changed: global -> reg (prefetched) -> ds_write_b128 ->
// ds_read_b128. Staging map: 16B chunk c = i*256+tid -> LDS offset c*16B,
// i.e. row=c>>3 (128 rows), k-chunk kc=c&7 (8 per row) — trivially bijective,
// identical formula on write and read, NO swizzle.
// C[M,N] = A[M,K](bf16) * Bt[N,K]^T(bf16). 4 waves (2x2), 128x128, BK=64.
//   OUTM=0: row-major C.  OUTM=1: Wo epilogue split (a / state / discard).
// ---------------------------------------------------------------------------
template <typename TC, int ACT, int OUTM>
__global__ __launch_bounds__(256) void mfma_lds(
    const bf16* __restrict__ A,
    const bf16* __restrict__ Bt0, const bf16* __restrict__ Bt1, const bf16* __restrict__ Bt2,
    TC* __restrict__ C0, TC* __restrict__ C1, TC* __restrict__ C2,
    const void* __restrict__ bias, int M, int N, int K, int seg,
    const int* __restrict__ flag)
{
    const int f32w = flag[0];
    const bf16* Bt = (blockIdx.z == 0) ? Bt0 : (blockIdx.z == 1 ? Bt1 : Bt2);
    TC* C = (blockIdx.z == 0) ? C0 : (blockIdx.z == 1 ? C1 : C2);

    __shared__ __align__(16) short As[128 * 64];
    __shared__ __align__(16) short Bs[128 * 64];

    const int tid = threadIdx.x;
    const int lane = tid & 63;
    const int w = tid >> 6;
    const int wm = w >> 1, wn = w & 1;
    const int bm = blockIdx.x * 128, bn = blockIdx.y * 128;

    f32x4 acc[4][4];
#pragma unroll
    for (int i = 0; i < 4; ++i)
#pragma unroll
        for (int j = 0; j < 4; ++j) acc[i][j] = (f32x4){0.f, 0.f, 0.f, 0.f};

    // preload tile k0=0 into registers
    bf16x8 rA[4], rB[4];
#pragma unroll
    for (int i = 0; i < 4; ++i) {
        int c = i * 256 + tid;
        int row = c >> 3, kc = c & 7;
        rA[i] = *(const bf16x8*)(A + (size_t)(bm + row) * K + kc * 8);
        rB[i] = *(const bf16x8*)(Bt + (size_t)(bn + row) * K + kc * 8);
    }

    for (int k0 = 0; k0 < K; k0 += 64) {
        __syncthreads();  // all waves done reading previous tile
#pragma unroll
        for (int i = 0; i < 4; ++i) {
            *(bf16x8*)&As[(size_t)(i * 256 + tid) * 8] = rA[i];
            *(bf16x8*)&Bs[(size_t)(i * 256 + tid) * 8] = rB[i];
        }
        if (k0 + 64 < K) {  // prefetch next tile; latency hides under compute
            int kn = k0 + 64;
#pragma unroll
            for (int i = 0; i < 4; ++i) {
                int c = i * 256 + tid;
                int row = c >> 3, kc = c & 7;
                rA[i] = *(const bf16x8*)(A + (size_t)(bm + row) * K + kn + kc * 8);
                rB[i] = *(const bf16x8*)(Bt + (size_t)(bn + row) * K + kn + kc * 8);
            }
        }
        __syncthreads();  // ds_writes visible to all waves

#pragma unroll
        for (int kh = 0; kh < 2; ++kh) {
            bf16x8 av[4], bv[4];
#pragma unroll
            for (int mi = 0; mi < 4; ++mi) {
                int r = wm * 64 + mi * 16 + (lane & 15);
                int cl = kh * 4 + (lane >> 4);
                av[mi] = *(const bf16x8*)&As[r * 64 + cl * 8];
            }
#pragma unroll
            for (int nj = 0; nj < 4; ++nj) {
                int r = wn * 64 + nj * 16 + (lane & 15);
                int cl = kh * 4 + (lane >> 4);
                bv[nj] = *(const bf16x8*)&Bs[r * 64 + cl * 8];
            }
#pragma unroll
            for (int mi = 0; mi < 4; ++mi)
#pragma unroll
                for (int nj = 0; nj < 4; ++nj)
                    acc[mi][nj] = __builtin_amdgcn_mfma_f32_16x16x32_bf16(
                        av[mi], bv[nj], acc[mi][nj], 0, 0, 0);
        }
    }

    // C/D layout: col=lane&15, row=(lane>>4)*4+reg  [proven rounds 6/7/8/9]
#pragma unroll
    for (int mi = 0; mi < 4; ++mi) {
#pragma unroll
        for (int nj = 0; nj < 4; ++nj) {
            int c = bn + wn * 64 + nj * 16 + (lane & 15);
            float bia = bias ? ldin(bias, c, f32w) : 0.f;
#pragma unroll
            for (int r = 0; r < 4; ++r) {
                int row = bm + wm * 64 + mi * 16 + (lane >> 4) * 4 + r;
                float v = acc[mi][nj][r] + bia;
                if (ACT == 1) v = 0.5f * v * (1.0f + erff(v * 0.70710678118654752f));
                if (OUTM == 0) {
                    storev(C + (size_t)row * N + c, v);
                } else {
                    int bb2 = row / CT, t = row % CT;
                    if (t >= CST) {
                        if (t < CST + CL)
                            storev(C0 + ((size_t)bb2 * CS + (size_t)seg * CL + (t - CST)) * CD + c, v);
                        else
                            storev(C1 + ((size_t)bb2 * CST + (t - CST - CL)) * CD + c, v);
                    }
                }
            }
        }
    }
}

// ---------------------------------------------------------------------------
// Causal attention v3 (PROVEN round 9): one wave per (b,h, 4 query rows).
// FUSE=1: epilogue applies proj1 + RoPE, writes q1/k1/v1 head-major.
// ---------------------------------------------------------------------------
template <typename TO, int FUSE>
__global__ __launch_bounds__(64) void attn_kernel3(
    const float* __restrict__ q, const float* __restrict__ k, const float* __restrict__ v,
    TO* __restrict__ o,
    int sb, int st, int sh, int ob, int ot, int oh,
    const void* __restrict__ Wq1, const void* __restrict__ Wk1, const void* __restrict__ Wv1,
    float* __restrict__ q1o, float* __restrict__ k1o, float* __restrict__ v1o,
    const int* __restrict__ flag)
{
    int t0 = blockIdx.x * 4, hh = blockIdx.y, b = blockIdx.z;
    int lane = threadIdx.x;
    __shared__ float qs[4][64];
    __shared__ float ps[4][64];

    const size_t hb = (size_t)b * sb + (size_t)hh * sh;
#pragma unroll
    for (int qi = 0; qi < 4; ++qi)
        qs[qi][lane] = q[hb + (size_t)(t0 + qi) * st + lane];
    __syncthreads();

    float m[4], l[4], acc[4];
#pragma unroll
    for (int qi = 0; qi < 4; ++qi) { m[qi] = -1e30f; l[qi] = 0.f; acc[qi] = 0.f; }

    const int tmax = t0 + 3;
    for (int j0 = 0; j0 <= tmax; j0 += 64) {
        int jj = j0 + lane;
        float sd[4] = {0.f, 0.f, 0.f, 0.f};
        if (jj <= tmax) {
            const float* kr = k + hb + (size_t)jj * st;
#pragma unroll
            for (int dd = 0; dd < 16; ++dd) {
                float4 k4 = *(const float4*)(kr + dd * 4);
#pragma unroll
                for (int qi = 0; qi < 4; ++qi) {
                    float4 q4 = *(const float4*)(&qs[qi][dd * 4]);
                    sd[qi] += k4.x * q4.x + k4.y * q4.y + k4.z * q4.z + k4.w * q4.w;
                }
            }
        }
        float corr[4], pnew[4];
#pragma unroll
        for (int qi = 0; qi < 4; ++qi) {
            float s = (jj <= t0 + qi) ? sd[qi] * 0.125f : -1e30f;
            float pm = s;
#pragma unroll
            for (int off = 32; off; off >>= 1) pm = fmaxf(pm, __shfl_xor(pm, off));
            float mn = fmaxf(m[qi], pm);
            corr[qi] = __expf(m[qi] - mn);
            float p = __expf(s - mn);
            float psum = p;
#pragma unroll
            for (int off = 32; off; off >>= 1) psum += __shfl_xor(psum, off);
            l[qi] = l[qi] * corr[qi] + psum;
            m[qi] = mn;
            pnew[qi] = p;
        }
        __syncthreads();
#pragma unroll
        for (int qi = 0; qi < 4; ++qi) ps[qi][lane] = pnew[qi];
        __syncthreads();

        // PV: fixed 64 keys (p=0 beyond valid); V rows j0+j <= 639 in-bounds.
        float a2a[4] = {0.f, 0.f, 0.f, 0.f}, a2b[4] = {0.f, 0.f, 0.f, 0.f};
        const float* vr = v + hb + (size_t)j0 * st + lane;
#pragma unroll
        for (int j4 = 0; j4 < 64; j4 += 8) {
            float vv[8];
#pragma unroll
            for (int u = 0; u < 8; ++u) vv[u] = vr[(size_t)(j4 + u) * st];
#pragma unroll
            for (int qi = 0; qi < 4; ++qi) {
                float4 pa = *(const float4*)&ps[qi][j4];
                float4 pb = *(const float4*)&ps[qi][j4 + 4];
                a2a[qi] += pa.x * vv[0] + pa.y * vv[1] + pa.z * vv[2] + pa.w * vv[3];
                a2b[qi] += pb.x * vv[4] + pb.y * vv[5] + pb.z * vv[6] + pb.w * vv[7];
            }
        }
#pragma unroll
        for (int qi = 0; qi < 4; ++qi) acc[qi] = acc[qi] * corr[qi] + a2a[qi] + a2b[qi];
    }

    if (FUSE == 0) {
#pragma unroll
        for (int qi = 0; qi < 4; ++qi)
            storev(&o[(size_t)b * ob + (size_t)hh * oh + (size_t)(t0 + qi) * ot + lane],
                   acc[qi] / l[qi]);
    } else {
        const int f32w = flag[0];
        __syncthreads();
#pragma unroll
        for (int qi = 0; qi < 4; ++qi) qs[qi][lane] = acc[qi] / l[qi];  // reuse qs as os
        __syncthreads();
        size_t wb = (size_t)hh * 4096;
        float aq[4] = {0.f, 0.f, 0.f, 0.f}, ak[4] = {0.f, 0.f, 0.f, 0.f},
              av[4] = {0.f, 0.f, 0.f, 0.f};
#pragma unroll 8
        for (int vv = 0; vv < 64; ++vv) {
            float wq = ldin(Wq1, wb + vv * 64 + lane, f32w);
            float wk = ldin(Wk1, wb + vv * 64 + lane, f32w);
            float wv = ldin(Wv1, wb + vv * 64 + lane, f32w);
#pragma unroll
            for (int qi = 0; qi < 4; ++qi) {
                float ov = qs[qi][vv];
                aq[qi] += ov * wq; ak[qi] += ov * wk; av[qi] += ov * wv;
            }
        }
        int i = lane >> 1;
        float inv = powf(10000.f, -(float)(2 * i) / 64.f);
#pragma unroll
        for (int qi = 0; qi < 4; ++qi) {
            int t = t0 + qi;
            float ang = (float)t * inv;
            float sn, cs;
            sincosf(ang, &sn, &cs);
            float oq = __shfl_xor(aq[qi], 1);
            float ok = __shfl_xor(ak[qi], 1);
            float rq, rk;
            if (lane & 1) { rq = oq * sn + aq[qi] * cs; rk = ok * sn + ak[qi] * cs; }
            else          { rq = aq[qi] * cs - oq * sn; rk = ak[qi] * cs - ok * sn; }
            size_t rowoff = ((size_t)(b * CH + hh) * CT + t) * 64;
            q1o[rowoff + lane] = rq;
            k1o[rowoff + lane] = rk;
            v1o[rowoff + lane] = av[qi];
        }
    }
}

// RoPE over ROW-MAJOR q0r and k0r [b*CT+t][h*64+d], thread per (b,t,h,pair)
__global__ __launch_bounds__(256) void rope_qk_rm_kernel(
    float* __restrict__ q, float* __restrict__ k)
{
    int idx = blockIdx.x * 256 + threadIdx.x;  // CB*CT*CH*32
    int i = idx & 31;
    int hh = (idx >> 5) & 7;
    int bt = idx >> 8;                          // b*CT + t
    int t = bt % CT;
    float inv = powf(10000.f, -(float)(2 * i) / 64.f);
    float ang = (float)t * inv;
    float sn, cs;
    sincosf(ang, &sn, &cs);
    size_t p = (size_t)bt * 512 + hh * 64 + 2 * i;
    float x1 = q[p], x2 = q[p + 1];
    q[p] = x1 * cs - x2 * sn;
    q[p + 1] = x1 * sn + x2 * cs;
    x1 = k[p]; x2 = k[p + 1];
    k[p] = x1 * cs - x2 * sn;
    k[p + 1] = x1 * sn + x2 * cs;
}

// toks = concat([state, x_seg, state]) -> bf16 (feeds MFMA A operand)
__global__ __launch_bounds__(256) void build_toks_kernel(
    const void* __restrict__ x, const float* __restrict__ state, bf16* __restrict__ toks,
    int seg, const int* __restrict__ flag)
{
    const int f32w = flag[0];
    int idx = blockIdx.x * 256 + threadIdx.x;  // B*T*D
    int d = idx & (CD - 1);
    int t = (idx >> 10) % CT;
    int b = idx / (CT * CD);
    float v;
    if (t < CST) v = state[(b * CST + t) * CD + d];
    else if (t < CST + CL) v = ldin(x, ((size_t)b * CS + seg * CL + (t - CST)) * CD + d, f32w);
    else v = state[(b * CST + (t - CST - CL)) * CD + d];
    toks[idx] = __float2bfloat16(v);
}

__global__ __launch_bounds__(256) void init_state_kernel(
    const void* __restrict__ s0, float* __restrict__ state, const int* __restrict__ flag)
{
    const int f32w = flag[0];
    int idx = blockIdx.x * 256 + threadIdx.x;  // B*ST*D
    state[idx] = ldin(s0, idx % (CST * CD), f32w);
}

// LayerNorm(ra + x) * g + b.
__global__ __launch_bounds__(256) void ln_kernel(
    const float* __restrict__ ra, const void* __restrict__ x,
    const void* __restrict__ g, const void* __restrict__ bb,
    void* __restrict__ outp, int out_ext, const int* __restrict__ flag)
{
    const int f32w = flag[0];
    int row = blockIdx.x;
    int tid = threadIdx.x;
    __shared__ float buf[CD];
    __shared__ float red[4];

    float s = 0.f;
    for (int c = tid; c < CD; c += 256) {
        float v = ra[(size_t)row * CD + c] + ldin(x, (size_t)row * CD + c, f32w);
        buf[c] = v;
        s += v;
    }
#pragma unroll
    for (int off = 32; off; off >>= 1) s += __shfl_xor(s, off);
    if ((tid & 63) == 0) red[tid >> 6] = s;
    __syncthreads();
    float mu = (red[0] + red[1] + red[2] + red[3]) * (1.f / CD);
    __syncthreads();

    float vs = 0.f;
    for (int c = tid; c < CD; c += 256) {
        float d0 = buf[c] - mu;
        vs += d0 * d0;
    }
#pragma unroll
    for (int off = 32; off; off >>= 1) vs += __shfl_xor(vs, off);
    if ((tid & 63) == 0) red[tid >> 6] = vs;
    __syncthreads();
    float var = (red[0] + red[1] + red[2] + red[3]) * (1.f / CD);
    float rs = rsqrtf(var + 1e-5f);

    for (int c = tid; c < CD; c += 256) {
        float y = (buf[c] - mu) * rs * ldin(g, c, f32w) + ldin(bb, c, f32w);
        size_t idx = (size_t)row * CD + c;
        if (!out_ext) {
            ((bf16*)outp)[idx] = __float2bfloat16(y);
        } else if (f32w) {
            ((float*)outp)[idx] = y;
        } else {
            ((bf16*)outp)[idx] = __float2bfloat16(y);
        }
    }
}

extern "C" void kernel_launch(void* const* d_in, const int* in_sizes, int n_in,
                              void* d_out, int out_size, void* d_ws, size_t ws_size,
                              hipStream_t stream)
{
    const void* x      = d_in[0];
    const void* s0     = d_in[1];
    const void* Wq0    = d_in[2];
    const void* Wk0    = d_in[3];
    const void* Wv0    = d_in[4];
    const void* Wq1    = d_in[5];
    const void* Wk1    = d_in[6];
    const void* Wv1    = d_in[7];
    const void* Wo     = d_in[8];
    const void* bo     = d_in[9];
    const void* g_attn = d_in[10];
    const void* b_attn = d_in[11];
    const void* W1     = d_in[12];
    const void* b1     = d_in[13];
    const void* W2     = d_in[14];
    const void* b2     = d_in[15];
    const void* g_mlp  = d_in[16];
    const void* b_mlp  = d_in[17];

    // workspace slot layout BYTE-IDENTICAL to passing rounds 2/6/7/8/9
    int* flag = (int*)d_ws;
    float* f = (float*)((char*)d_ws + 16);
    float* toks_slot = f; f += (size_t)CB * CT * CD;       // bf16 toks
    float* q0 = f;      f += (size_t)CB * CH * CT * 64;    // row-major q0r [1280][512]
    float* k0 = f;      f += (size_t)CB * CH * CT * 64;
    float* v0 = f;      f += (size_t)CB * CH * CT * 64;
    float* o0 = f;      f += (size_t)CB * CH * CT * 64;    // (unused now)
    float* q1 = f;      f += (size_t)CB * CH * CT * 64;    // head-major
    float* k1 = f;      f += (size_t)CB * CH * CT * 64;
    float* v1 = f;      f += (size_t)CB * CH * CT * 64;
    float* o1t_slot = f; f += (size_t)CB * CT * (CH * 64); // bf16 o1t [1280][512]
    float* seg_out = f; f += (size_t)CB * CT * CD;         // (unused now)
    float* state = f;   f += (size_t)CB * CST * CD;
    float* a = f;       f += (size_t)CB * CS * CD;
    bf16* h = (bf16*)f;                                    // LN1 out [B*S, D] bf16
    bf16* g1 = h + (size_t)CB * CS * CD;                   // MLP mid chunk [MCH, DH] bf16

    bf16* toks = (bf16*)toks_slot;
    bf16* o1t  = (bf16*)o1t_slot;
    bf16* WtQ = h;                                         // h region dead until LN1
    bf16* WtK = WtQ + (size_t)512 * 1024;
    bf16* WtV = WtK + (size_t)512 * 1024;
    bf16* WtO = WtV + (size_t)512 * 1024;                  // [1024][512]
    bf16* Wt1 = (bf16*)toks_slot;                          // seg region dead during MLP
    bf16* Wt2 = Wt1 + (size_t)CDH * CD;

    sniff_kernel<<<1, 64, 0, stream>>>(x, flag);
    init_state_kernel<<<(CB * CST * CD) / 256, 256, 0, stream>>>(s0, state, flag);

    transpose_kernel<<<dim3(8, 16), 256, 0, stream>>>(Wq0, WtQ, CD, 512, flag);
    transpose_kernel<<<dim3(8, 16), 256, 0, stream>>>(Wk0, WtK, CD, 512, flag);
    transpose_kernel<<<dim3(8, 16), 256, 0, stream>>>(Wv0, WtV, CD, 512, flag);
    transpose_kernel<<<dim3(16, 8), 256, 0, stream>>>(Wo, WtO, 512, CD, flag);

    for (int seg = 0; seg < NSEG; ++seg) {
        build_toks_kernel<<<(CB * CT * CD) / 256, 256, 0, stream>>>(x, state, toks, seg, flag);
        // q0r,k0r,v0r = toks @ {Wq0,Wk0,Wv0}, row-major [1280][512]
        mfma_lds<float, 0, 0><<<dim3(10, 4, 3), 256, 0, stream>>>(
            toks, WtQ, WtK, WtV, q0, k0, v0, nullptr, CB * CT, 512, CD, 0, flag);
        rope_qk_rm_kernel<<<(CB * CT * CH * 32) / 256, 256, 0, stream>>>(q0, k0);
        // attn1 (row-major in) fused with proj1+RoPE -> q1/k1/v1 head-major
        attn_kernel3<float, 1><<<dim3(CT / 4, CH, CB), 64, 0, stream>>>(
            q0, k0, v0, o0,
            CT * 512, 512, 64, 0, 0, 0,
            Wq1, Wk1, Wv1, q1, k1, v1, flag);
        // attn2 (head-major in) -> token-major bf16 o1t [1280][512]
        attn_kernel3<bf16, 0><<<dim3(CT / 4, CH, CB), 64, 0, stream>>>(
            q1, k1, v1, o1t,
            CH * CT * 64, 64, CT * 64, CT * 512, 512, 64,
            nullptr, nullptr, nullptr, nullptr, nullptr, nullptr, flag);
        // Wo GEMM with fused epilogue split: middle L rows -> a, last ST -> state
        mfma_lds<float, 0, 1><<<dim3(10, 8, 1), 256, 0, stream>>>(
            o1t, WtO, WtO, WtO, a, state, a, bo, CB * CT, CD, 512, seg, flag);
    }

    // h = LN(a + x) -> bf16 internal (overwrites WtQ..WtO — dead by now)
    ln_kernel<<<CB * CS, 256, 0, stream>>>(a, x, g_attn, b_attn, h, 0, flag);

    transpose_kernel<<<dim3(CDH / 64, CD / 64), 256, 0, stream>>>(W1, Wt1, CD, CDH, flag);
    transpose_kernel<<<dim3(CD / 64, CDH / 64), 256, 0, stream>>>(W2, Wt2, CDH, CD, flag);

    for (int c = 0; c < (CB * CS) / MCH; ++c) {
        mfma_lds<bf16, 1, 0><<<dim3(MCH / 128, CDH / 128, 1), 256, 0, stream>>>(
            h + (size_t)c * MCH * CD, Wt1, Wt1, Wt1, g1, g1, g1, b1, MCH, CDH, CD, 0, flag);
        mfma_lds<float, 0, 0><<<dim3(MCH / 128, CD / 128, 1), 256, 0, stream>>>(
            g1, Wt2, Wt2, Wt2, a + (size_t)c * MCH * CD, a, a, b2, MCH, CD, CDH, 0, flag);
    }
    ln_kernel<<<CB * CS, 256, 0, stream>>>(a, x, g_mlp, b_mlp, d_out, 1, flag);
}